// Round 10
// baseline (337.282 us; speedup 1.0000x reference)
//
#include <hip/hip_runtime.h>
#include <math.h>

#define C_DIM 128
#define POOL_CHUNK 64
#define BKT_SHIFT 7          // 128 nodes per destination bucket
#define MAX_B 1024           // LDS histogram capacity (B = ceil(N/128) = 782)
#define CB 128               // edge chunk blocks (128 -> 256B runs in bscatter)
#define FB_CAP 8192          // bfinal LDS edge-staging capacity (avg bucket ~2048)
#define NPART 8              // XCD partitions for pool partial sums
typedef unsigned short ushort_t;
typedef __attribute__((ext_vector_type(8))) short short8;
typedef __attribute__((ext_vector_type(4))) float f32x4;

static inline int ceil_div(int a, int b) { return (a + b - 1) / b; }

// bf16 round-to-nearest-even (unbiased — truncation would bias sums)
__device__ inline ushort_t f2bf(float f) {
    union { float f; unsigned u; } v; v.f = f;
    unsigned r = v.u + 0x7FFFu + ((v.u >> 16) & 1u);
    return (ushort_t)(r >> 16);
}
__device__ inline float bf2f(unsigned s) {
    union { unsigned u; float f; } v; v.u = s << 16; return v.f;
}
__device__ inline float bf_lo(unsigned u) {
    union { unsigned v; float f; } c; c.v = u << 16; return c.f;
}
__device__ inline float bf_hi(unsigned u) {
    union { unsigned v; float f; } c; c.v = u & 0xFFFF0000u; return c.f;
}
__device__ inline void accum8(uint4 u, float acc[8]) {
    acc[0] += bf_lo(u.x); acc[1] += bf_hi(u.x);
    acc[2] += bf_lo(u.y); acc[3] += bf_hi(u.y);
    acc[4] += bf_lo(u.z); acc[5] += bf_hi(u.z);
    acc[6] += bf_lo(u.w); acc[7] += bf_hi(u.w);
}

// ============ CSR build: two-level bucket sort, LDS atomics only ============

// Pass A (fused): blocks < CB do the bucket histogram + zero gsums/cursor;
// blocks CB..CB+1 pack W1/W2 into MFMA B-fragment layout.
__global__ __launch_bounds__(256) void k_bcount(
    const int* __restrict__ col, int E, int chunk, int B,
    int* __restrict__ counts,
    const float* __restrict__ W1, const float* __restrict__ W2,
    uint4* __restrict__ wf1, uint4* __restrict__ wf2,
    float* __restrict__ gsums, int GC8, int* __restrict__ cursor) {
    int t = threadIdx.x, blk = blockIdx.x;
    if (blk >= CB) {   // weight fragment pre-pack
        const float* W = (blk == CB) ? W1 : W2;
        uint4* wf = (blk == CB) ? wf1 : wf2;
        for (int f = t; f < 2048; f += 256) {
            int lane = f & 63, kkn = f >> 6;
            int kk = kkn & 3, nt = kkn >> 2;
            int n = lane & 15, quad = lane >> 4;
            union { ushort_t h[8]; uint4 v; } u;
#pragma unroll
            for (int j = 0; j < 8; ++j)
                u.h[j] = f2bf(W[(size_t)(kk * 32 + quad * 8 + j) * C_DIM + nt * 16 + n]);
            wf[f] = u.v;
        }
        return;
    }
    // zero gsums partials + cursor (pool_sum runs much later in the stream)
    for (int i = blk * 256 + t; i < GC8; i += CB * 256) gsums[i] = 0.f;
    if (blk == 0 && t == 0) *cursor = 0;

    __shared__ int hist[MAX_B];
    for (int i = t; i < B; i += 256) hist[i] = 0;
    __syncthreads();
    int s = blk * chunk;                     // chunk % 4 == 0, E % 4 == 0
    int e = s + chunk; if (e > E) e = E;
    for (int i = s + 4 * t; i < e; i += 1024) {
        int4 c = *(const int4*)(col + i);
        atomicAdd(&hist[c.x >> BKT_SHIFT], 1);
        atomicAdd(&hist[c.y >> BKT_SHIFT], 1);
        atomicAdd(&hist[c.z >> BKT_SHIFT], 1);
        atomicAdd(&hist[c.w >> BKT_SHIFT], 1);
    }
    __syncthreads();
    for (int i = t; i < B; i += 256)
        counts[(size_t)i * CB + blk] = hist[i];
}

// Pass B: per-bucket exclusive scan over CB block counts; bucket base claimed
// from a global cursor (order-free — offs are per-node (start,end) pairs).
__global__ __launch_bounds__(CB) void k_bscan(
    int* __restrict__ counts, int* __restrict__ bbase, int* __restrict__ btot,
    int* __restrict__ cursor) {
    __shared__ int sd[CB];
    int b = blockIdx.x, t = threadIdx.x;
    int v = counts[(size_t)b * CB + t];
    sd[t] = v;
    __syncthreads();
    for (int off = 1; off < CB; off <<= 1) {
        int x = (t >= off) ? sd[t - off] : 0;
        __syncthreads();
        sd[t] += x;
        __syncthreads();
    }
    counts[(size_t)b * CB + t] = sd[t] - v;   // exclusive within bucket
    if (t == CB - 1) {
        btot[b] = sd[CB - 1];
        bbase[b] = atomicAdd(cursor, sd[CB - 1]);
    }
}

// Pass C: scatter edges to bucket order, PACKED: (src << 7) | (col & 127).
__global__ __launch_bounds__(256) void k_bscatter(
    const int* __restrict__ row, const int* __restrict__ col, int E, int chunk,
    int B, const int* __restrict__ counts, const int* __restrict__ bbase,
    int* __restrict__ epk) {
    __shared__ int cur[MAX_B];
    int t = threadIdx.x, blk = blockIdx.x;
    for (int i = t; i < B; i += 256)
        cur[i] = bbase[i] + counts[(size_t)i * CB + blk];
    __syncthreads();
    int s = blk * chunk;
    int e = s + chunk; if (e > E) e = E;
    for (int i = s + 4 * t; i < e; i += 1024) {
        int4 c = *(const int4*)(col + i);
        int4 r = *(const int4*)(row + i);
        int s0 = atomicAdd(&cur[c.x >> BKT_SHIFT], 1); epk[s0] = (r.x << 7) | (c.x & 127);
        int s1 = atomicAdd(&cur[c.y >> BKT_SHIFT], 1); epk[s1] = (r.y << 7) | (c.y & 127);
        int s2 = atomicAdd(&cur[c.z >> BKT_SHIFT], 1); epk[s2] = (r.z << 7) | (c.z & 127);
        int s3 = atomicAdd(&cur[c.w >> BKT_SHIFT], 1); epk[s3] = (r.w << 7) | (c.w & 127);
    }
}

// Pass D: one block per bucket — LDS-stage edges, count, scan, write per-node
// (start,end) pairs + dinv, scatter csr.
__global__ __launch_bounds__(256) void k_bfinal(
    const int* __restrict__ epk, const int* __restrict__ bbase,
    const int* __restrict__ btot, int N,
    int2* __restrict__ offs2, float* __restrict__ dinv, int* __restrict__ csr) {
    __shared__ int sh[FB_CAP];
    __shared__ int cnt[128];
    __shared__ int pre[128];
    __shared__ int cur[128];
    int bkt = blockIdx.x, t = threadIdx.x;
    int s = bbase[bkt];
    int m = btot[bkt];
    int e = s + m;
    int base = bkt << BKT_SHIFT;
    int nn = N - base; if (nn > 128) nn = 128;
    bool fits = (m <= FB_CAP);
    if (t < 128) cnt[t] = 0;
    __syncthreads();
    if (fits) {
        for (int i = t; i < m; i += 256) {
            int u = epk[s + i];
            sh[i] = u;
            atomicAdd(&cnt[u & 127], 1);
        }
    } else {
        for (int i = s + t; i < e; i += 256)
            atomicAdd(&cnt[epk[i] & 127], 1);
    }
    __syncthreads();
    if (t < 128) pre[t] = cnt[t];
    __syncthreads();
    for (int off = 1; off < 128; off <<= 1) {
        int x = (t >= off && t < 128) ? pre[t - off] : 0;
        __syncthreads();
        if (t < 128) pre[t] += x;
        __syncthreads();
    }
    if (t < 128) {
        int ex = pre[t] - cnt[t];
        cur[t] = ex;
        if (t < nn) {
            offs2[base + t] = make_int2(s + ex, s + ex + cnt[t]);
            dinv[base + t] = 1.0f / sqrtf((float)cnt[t] + 1.0f);
        }
    }
    __syncthreads();
    if (fits) {
        for (int i = t; i < m; i += 256) {
            int u = sh[i];
            int slot = atomicAdd(&cur[u & 127], 1);
            csr[s + slot] = u >> 7;
        }
    } else {
        for (int i = s + t; i < e; i += 256) {
            int u = epk[i];
            int slot = atomicAdd(&cur[u & 127], 1);
            csr[s + slot] = u >> 7;
        }
    }
}

// ============ MFMA matmul [N,128]@[128,128] -> bf16 table, scaled by dinv ===
template <int ABF16>
__global__ __launch_bounds__(256) void k_matmul_mfma(
    const float* __restrict__ Af, const ushort_t* __restrict__ Abf,
    const uint4* __restrict__ wfrag, const float* __restrict__ dinv,
    ushort_t* __restrict__ Cb, int N) {
    __shared__ uint4 wfs[2048];                    // 32 KB
    __shared__ __align__(16) ushort_t eb[64 * 136]; // 17.4 KB
    int t = threadIdx.x;
    int wv = t >> 6, lane = t & 63;
    int n = lane & 15, quad = lane >> 4;
    int row0 = blockIdx.x * 128;

    for (int i = t; i < 2048; i += 256) wfs[i] = wfrag[i];

    int rA[2];
#pragma unroll
    for (int tl = 0; tl < 2; ++tl) {
        int r = row0 + wv * 32 + tl * 16 + n;
        rA[tl] = r < N ? r : N - 1;                // clamp (never stored)
    }

    f32x4 acc[2][8];
#pragma unroll
    for (int tl = 0; tl < 2; ++tl)
#pragma unroll
        for (int i = 0; i < 8; ++i) acc[tl][i] = (f32x4){0.f, 0.f, 0.f, 0.f};

    __syncthreads();

#pragma unroll
    for (int kk = 0; kk < 4; ++kk) {
        short8 a[2];
#pragma unroll
        for (int tl = 0; tl < 2; ++tl) {
            if (ABF16) {
                uint4 u = *(const uint4*)(Abf + (size_t)rA[tl] * C_DIM + kk * 32 + quad * 8);
                union { uint4 v; short8 s; } c; c.v = u;
                a[tl] = c.s;
            } else {
                const float4* ap = (const float4*)(Af + (size_t)rA[tl] * C_DIM + kk * 32 + quad * 8);
                float4 f0 = ap[0], f1 = ap[1];
                union { ushort_t h[8]; short8 s; } c;
                c.h[0] = f2bf(f0.x); c.h[1] = f2bf(f0.y); c.h[2] = f2bf(f0.z); c.h[3] = f2bf(f0.w);
                c.h[4] = f2bf(f1.x); c.h[5] = f2bf(f1.y); c.h[6] = f2bf(f1.z); c.h[7] = f2bf(f1.w);
                a[tl] = c.s;
            }
        }
#pragma unroll
        for (int nt = 0; nt < 8; ++nt) {
            uint4 bu = wfs[(nt * 4 + kk) * 64 + lane];
            union { uint4 v; short8 s; } c; c.v = bu;
            acc[0][nt] = __builtin_amdgcn_mfma_f32_16x16x32_bf16(a[0], c.s, acc[0][nt], 0, 0, 0);
            acc[1][nt] = __builtin_amdgcn_mfma_f32_16x16x32_bf16(a[1], c.s, acc[1][nt], 0, 0, 0);
        }
    }

#pragma unroll
    for (int pass = 0; pass < 2; ++pass) {
        __syncthreads();
#pragma unroll
        for (int reg = 0; reg < 4; ++reg) {
            int lr = quad * 4 + reg;
            int grow = row0 + wv * 32 + pass * 16 + lr;
            float sc = dinv[grow < N ? grow : N - 1];
#pragma unroll
            for (int nt = 0; nt < 8; ++nt)
                eb[(wv * 16 + lr) * 136 + nt * 16 + n] = f2bf(acc[pass][nt][reg] * sc);
        }
        __syncthreads();
        for (int idx = t; idx < 16 * 64; idx += 256) {
            int r = idx >> 4, c8 = idx & 15;
            int grow = row0 + (r >> 4) * 32 + pass * 16 + (r & 15);
            if (grow < N)
                *(uint4*)(Cb + (size_t)grow * C_DIM + c8 * 8) =
                    *(const uint4*)&eb[r * 136 + c8 * 8];
        }
    }
}

// ---------------- per-node gather-reduce aggregation (bf16 in/out) -----------
// r7 form (fastest measured): one wave per node; 16 lanes cover a 256 B row
// (uint4/lane); quad q takes edge j+4b+q; scalar dword csr loads; 8 fp32 accs;
// shfl_xor butterfly merges the 4 quads.
template <int RELU>
__global__ __launch_bounds__(256) void k_aggregate(
    const ushort_t* __restrict__ hs, const int2* __restrict__ offs2,
    const int* __restrict__ csr, const float* __restrict__ dinv,
    const float* __restrict__ bias, uint4* __restrict__ outV, int N) {
    int node = (blockIdx.x << 2) + (threadIdx.x >> 6);
    if (node >= N) return;
    int t = threadIdx.x & 63;
    int q = t >> 4;         // quad 0..3
    int fs = t & 15;        // feature slice: features 8*fs .. 8*fs+7
    int2 se = offs2[node];
    int s = se.x, e = se.y;

    float acc[8];
    {   // self-loop: quad 0 only
        uint4 u = *(const uint4*)(hs + (size_t)node * C_DIM + fs * 8);
        float v[8];
        v[0] = bf_lo(u.x); v[1] = bf_hi(u.x);
        v[2] = bf_lo(u.y); v[3] = bf_hi(u.y);
        v[4] = bf_lo(u.z); v[5] = bf_hi(u.z);
        v[6] = bf_lo(u.w); v[7] = bf_hi(u.w);
#pragma unroll
        for (int i = 0; i < 8; ++i) acc[i] = (q == 0) ? v[i] : 0.f;
    }

    int j = s;
    for (; j + 16 <= e; j += 16) {          // 16 edges: 4 idx + 4 row loads
        int r[4];
#pragma unroll
        for (int b = 0; b < 4; ++b) r[b] = csr[j + b * 4 + q];
        uint4 u[4];
#pragma unroll
        for (int b = 0; b < 4; ++b)
            u[b] = *(const uint4*)(hs + (size_t)r[b] * C_DIM + fs * 8);
#pragma unroll
        for (int b = 0; b < 4; ++b) accum8(u[b], acc);
    }
    for (; j + 4 <= e; j += 4) {            // 4-edge groups
        int r = csr[j + q];
        uint4 u = *(const uint4*)(hs + (size_t)r * C_DIM + fs * 8);
        accum8(u, acc);
    }
    if (j + q < e) {                        // tail 1-3 edges: one per quad
        int r = csr[j + q];
        uint4 u = *(const uint4*)(hs + (size_t)r * C_DIM + fs * 8);
        accum8(u, acc);
    }

#pragma unroll
    for (int i = 0; i < 8; ++i) {
        acc[i] += __shfl_xor(acc[i], 16);
        acc[i] += __shfl_xor(acc[i], 32);
    }

    if (q == 0) {
        float dn = dinv[node];
        float4 b0 = *(const float4*)(bias + fs * 8);
        float4 b1 = *(const float4*)(bias + fs * 8 + 4);
        float o[8];
        o[0] = dn * acc[0] + b0.x; o[1] = dn * acc[1] + b0.y;
        o[2] = dn * acc[2] + b0.z; o[3] = dn * acc[3] + b0.w;
        o[4] = dn * acc[4] + b1.x; o[5] = dn * acc[5] + b1.y;
        o[6] = dn * acc[6] + b1.z; o[7] = dn * acc[7] + b1.w;
        if (RELU) {
#pragma unroll
            for (int i = 0; i < 8; ++i) o[i] = fmaxf(o[i], 0.f);
        }
        uint4 pk;
        pk.x = (unsigned)f2bf(o[0]) | ((unsigned)f2bf(o[1]) << 16);
        pk.y = (unsigned)f2bf(o[2]) | ((unsigned)f2bf(o[3]) << 16);
        pk.z = (unsigned)f2bf(o[4]) | ((unsigned)f2bf(o[5]) << 16);
        pk.w = (unsigned)f2bf(o[6]) | ((unsigned)f2bf(o[7]) << 16);
        outV[(size_t)node * 16 + fs] = pk;
    }
}

// ---------------- pool stage 1: segmented partial sums (bf16 in) -------------
// Flushes go to the block's XCD partition (blockIdx&7) — atomics stay XCD-
// local instead of bouncing one hot gsums line across all 8 XCDs.
__global__ __launch_bounds__(128) void k_pool_sum(
    const ushort_t* __restrict__ h, const int* __restrict__ batch, int n,
    float* __restrict__ gsums, int GC) {
    int r0 = blockIdx.x * POOL_CHUNK;
    int r1 = r0 + POOL_CHUNK; if (r1 > n) r1 = n;
    if (r0 >= n) return;
    float* sums = gsums + (size_t)(blockIdx.x & (NPART - 1)) * GC;
    int t = threadIdx.x;
    int c = t & 63, rr = t >> 6;
    float2 acc = make_float2(0.f, 0.f);
    int g = batch[r0];
    int i = r0;
    while (i < r1) {
        if (i + 8 <= r1 && batch[i + 7] == g) {
#pragma unroll
            for (int b = 0; b < 4; ++b) {
                unsigned u = *(const unsigned*)(h + (size_t)(i + rr + 2 * b) * C_DIM + c * 2);
                acc.x += bf_lo(u); acc.y += bf_hi(u);
            }
            i += 8;
        } else {
            int bi = batch[i];
            if (bi != g) {
                atomicAdd(&sums[(size_t)g * C_DIM + c * 2], acc.x);
                atomicAdd(&sums[(size_t)g * C_DIM + c * 2 + 1], acc.y);
                acc = make_float2(0.f, 0.f); g = bi;
            }
            if (rr == 0) {
                unsigned u = *(const unsigned*)(h + (size_t)i * C_DIM + c * 2);
                acc.x += bf_lo(u); acc.y += bf_hi(u);
            }
            ++i;
        }
    }
    atomicAdd(&sums[(size_t)g * C_DIM + c * 2], acc.x);
    atomicAdd(&sums[(size_t)g * C_DIM + c * 2 + 1], acc.y);
}

// ---------------- pool stage 2: merge partials, mean + MLP (128->64->1) ------
__global__ __launch_bounds__(128) void k_mlp(
    const float* __restrict__ gsums, int GC, const int* __restrict__ batch, int n,
    const float* __restrict__ Wm1, const float* __restrict__ bm1,
    const float* __restrict__ Wm2, const float* __restrict__ bm2,
    float* __restrict__ out) {
    int g = blockIdx.x;
    int t = threadIdx.x;
    int lo = 0, hi = n;
    while (lo < hi) { int m = (lo + hi) >> 1; if (batch[m] < g) lo = m + 1; else hi = m; }
    int start = lo;
    lo = start; hi = n;
    while (lo < hi) { int m = (lo + hi) >> 1; if (batch[m] < g + 1) lo = m + 1; else hi = m; }
    float cnt = (float)(lo - start);

    float s = 0.f;
#pragma unroll
    for (int p = 0; p < NPART; ++p)
        s += gsums[(size_t)p * GC + (size_t)g * C_DIM + t];
    float mean = s / fmaxf(cnt, 1.0f);

    __shared__ float m_s[128];
    __shared__ float hid[64];
    m_s[t] = mean;
    __syncthreads();
    if (t < 64) {
        float a = bm1[t];
#pragma unroll 4
        for (int k = 0; k < 128; ++k) a += m_s[k] * Wm1[k * 64 + t];
        hid[t] = fmaxf(a, 0.f) * Wm2[t];
    }
    __syncthreads();
    if (t < 64) {
        float v = hid[t];
        for (int off = 32; off > 0; off >>= 1) v += __shfl_down(v, off);
        if (t == 0) out[g] = v + bm2[0];
    }
}

extern "C" void kernel_launch(void* const* d_in, const int* in_sizes, int n_in,
                              void* d_out, int out_size, void* d_ws, size_t ws_size,
                              hipStream_t stream) {
    const float* x     = (const float*)d_in[0];
    const int*   eidx  = (const int*)d_in[1];
    const int*   batch = (const int*)d_in[2];
    const float* W1    = (const float*)d_in[3];
    const float* b1    = (const float*)d_in[4];
    const float* W2    = (const float*)d_in[5];
    const float* b2    = (const float*)d_in[6];
    const float* Wm1   = (const float*)d_in[7];
    const float* bm1   = (const float*)d_in[8];
    const float* Wm2   = (const float*)d_in[9];
    const float* bm2   = (const float*)d_in[10];

    const int N = in_sizes[2];       // 100000
    const int E = in_sizes[1] / 2;   // 1600000 (E % 4 == 0)
    const int G = out_size;          // 512
    const int B = (N + 127) >> BKT_SHIFT;   // 782 buckets
    const int GC = G * C_DIM;

    char* p = (char*)d_ws;
    auto carve = [&](size_t bytes) {
        char* q = p;
        p += (bytes + 255) & ~(size_t)255;
        return q;
    };
    ushort_t* bufT   = (ushort_t*)carve((size_t)N * C_DIM * sizeof(ushort_t)); // matmul out
    ushort_t* bufA   = (ushort_t*)carve((size_t)N * C_DIM * sizeof(ushort_t)); // agg out
    float*    dinv   = (float*)   carve((size_t)N * sizeof(float));
    int2*     offs2  = (int2*)    carve((size_t)N * sizeof(int2));
    int*      csr    = (int*)     carve((size_t)E * sizeof(int));
    int*      counts = (int*)     carve((size_t)B * CB * sizeof(int));
    int*      btot   = (int*)     carve((size_t)B * sizeof(int));
    int*      bbase  = (int*)     carve((size_t)B * sizeof(int));
    float*    gsums  = (float*)   carve((size_t)NPART * GC * sizeof(float));
    uint4*    wf1    = (uint4*)   carve(2048 * sizeof(uint4));
    uint4*    wf2    = (uint4*)   carve(2048 * sizeof(uint4));
    int*      cursor = (int*)     carve(sizeof(int));
    // epk (packed (src<<7)|node, 6.4 MB) aliases bufT (dead until matmul1)
    int*      epk    = (int*)bufT;

    const int* erow = eidx;
    const int* ecol = eidx + E;
    const int chunk = (ceil_div(E, CB) + 3) & ~3;   // multiple of 4 for int4 loads

    // --- CSR-by-destination build (fused wfrag + gsums/cursor zeroing) ---
    k_bcount<<<CB + 2, 256, 0, stream>>>(ecol, E, chunk, B, counts,
                                         W1, W2, wf1, wf2, gsums, NPART * GC, cursor);
    k_bscan<<<B, CB, 0, stream>>>(counts, bbase, btot, cursor);
    k_bscatter<<<CB, 256, 0, stream>>>(erow, ecol, E, chunk, B, counts, bbase, epk);
    k_bfinal<<<B, 256, 0, stream>>>(epk, bbase, btot, N, offs2, dinv, csr);

    // --- conv1 ---
    k_matmul_mfma<0><<<ceil_div(N, 128), 256, 0, stream>>>(x, nullptr, wf1, dinv, bufT, N);
    k_aggregate<1><<<ceil_div(N, 4), 256, 0, stream>>>(bufT, offs2, csr, dinv, b1,
                                                       (uint4*)bufA, N);
    // --- conv2 ---
    k_matmul_mfma<1><<<ceil_div(N, 128), 256, 0, stream>>>(nullptr, bufA, wf2, dinv, bufT, N);
    k_aggregate<0><<<ceil_div(N, 4), 256, 0, stream>>>(bufT, offs2, csr, dinv, b2,
                                                       (uint4*)bufA, N);
    // --- pool (2-stage, XCD-partitioned partials) + MLP ---
    k_pool_sum<<<ceil_div(N, POOL_CHUNK), 128, 0, stream>>>(bufA, batch, N, gsums, GC);
    k_mlp<<<G, 128, 0, stream>>>(gsums, GC, batch, N, Wm1, bm1, Wm2, bm2, (float*)d_out);
}

// Round 11
// 323.999 us; speedup vs baseline: 1.0410x; 1.0410x over previous
//
#include <hip/hip_runtime.h>
#include <math.h>

#define C_DIM 128
#define POOL_CHUNK 64
#define BKT_SHIFT 7          // 128 nodes per destination bucket
#define MAX_B 1024           // LDS histogram capacity (B = ceil(N/128) = 782)
#define CB 256               // edge chunk blocks (r9 best)
#define FB_CAP 8192          // bfinal LDS edge-staging capacity (avg bucket ~2048)
typedef unsigned short ushort_t;
typedef __attribute__((ext_vector_type(8))) short short8;
typedef __attribute__((ext_vector_type(4))) float f32x4;

static inline int ceil_div(int a, int b) { return (a + b - 1) / b; }

// bf16 round-to-nearest-even (unbiased — truncation would bias sums)
__device__ inline ushort_t f2bf(float f) {
    union { float f; unsigned u; } v; v.f = f;
    unsigned r = v.u + 0x7FFFu + ((v.u >> 16) & 1u);
    return (ushort_t)(r >> 16);
}
__device__ inline float bf2f(unsigned s) {
    union { unsigned u; float f; } v; v.u = s << 16; return v.f;
}
__device__ inline float bf_lo(unsigned u) {
    union { unsigned v; float f; } c; c.v = u << 16; return c.f;
}
__device__ inline float bf_hi(unsigned u) {
    union { unsigned v; float f; } c; c.v = u & 0xFFFF0000u; return c.f;
}
__device__ inline void accum8(uint4 u, float acc[8]) {
    acc[0] += bf_lo(u.x); acc[1] += bf_hi(u.x);
    acc[2] += bf_lo(u.y); acc[3] += bf_hi(u.y);
    acc[4] += bf_lo(u.z); acc[5] += bf_hi(u.z);
    acc[6] += bf_lo(u.w); acc[7] += bf_hi(u.w);
}

// ============ CSR build: two-level bucket sort, LDS atomics only ============

// Pass A (fused): blocks < CB do the bucket histogram + zero gsums/cursor;
// blocks CB..CB+1 pack W1/W2 into MFMA B-fragment layout.
__global__ __launch_bounds__(256) void k_bcount(
    const int* __restrict__ col, int E, int chunk, int B,
    int* __restrict__ counts,
    const float* __restrict__ W1, const float* __restrict__ W2,
    uint4* __restrict__ wf1, uint4* __restrict__ wf2,
    float* __restrict__ gsums, int GC, int* __restrict__ cursor) {
    int t = threadIdx.x, blk = blockIdx.x;
    if (blk >= CB) {   // weight fragment pre-pack
        const float* W = (blk == CB) ? W1 : W2;
        uint4* wf = (blk == CB) ? wf1 : wf2;
        for (int f = t; f < 2048; f += 256) {
            int lane = f & 63, kkn = f >> 6;
            int kk = kkn & 3, nt = kkn >> 2;
            int n = lane & 15, quad = lane >> 4;
            union { ushort_t h[8]; uint4 v; } u;
#pragma unroll
            for (int j = 0; j < 8; ++j)
                u.h[j] = f2bf(W[(size_t)(kk * 32 + quad * 8 + j) * C_DIM + nt * 16 + n]);
            wf[f] = u.v;
        }
        return;
    }
    // zero gsums + cursor (pool_sum runs much later in the stream)
    for (int i = blk * 256 + t; i < GC; i += CB * 256) gsums[i] = 0.f;
    if (blk == 0 && t == 0) *cursor = 0;

    __shared__ int hist[MAX_B];
    for (int i = t; i < B; i += 256) hist[i] = 0;
    __syncthreads();
    int s = blk * chunk;                     // chunk % 4 == 0, E % 4 == 0
    int e = s + chunk; if (e > E) e = E;
    for (int i = s + 4 * t; i < e; i += 1024) {
        int4 c = *(const int4*)(col + i);
        atomicAdd(&hist[c.x >> BKT_SHIFT], 1);
        atomicAdd(&hist[c.y >> BKT_SHIFT], 1);
        atomicAdd(&hist[c.z >> BKT_SHIFT], 1);
        atomicAdd(&hist[c.w >> BKT_SHIFT], 1);
    }
    __syncthreads();
    for (int i = t; i < B; i += 256)
        counts[(size_t)i * CB + blk] = hist[i];
}

// Pass B: per-bucket exclusive scan over CB block counts; bucket base claimed
// from a global cursor (order-free — offs are per-node (start,end) pairs).
__global__ __launch_bounds__(CB) void k_bscan(
    int* __restrict__ counts, int* __restrict__ bbase, int* __restrict__ btot,
    int* __restrict__ cursor) {
    __shared__ int sd[CB];
    int b = blockIdx.x, t = threadIdx.x;
    int v = counts[(size_t)b * CB + t];
    sd[t] = v;
    __syncthreads();
    for (int off = 1; off < CB; off <<= 1) {
        int x = (t >= off) ? sd[t - off] : 0;
        __syncthreads();
        sd[t] += x;
        __syncthreads();
    }
    counts[(size_t)b * CB + t] = sd[t] - v;   // exclusive within bucket
    if (t == CB - 1) {
        btot[b] = sd[CB - 1];
        bbase[b] = atomicAdd(cursor, sd[CB - 1]);
    }
}

// Pass C: scatter edges to bucket order, PACKED: (src << 7) | (col & 127).
__global__ __launch_bounds__(256) void k_bscatter(
    const int* __restrict__ row, const int* __restrict__ col, int E, int chunk,
    int B, const int* __restrict__ counts, const int* __restrict__ bbase,
    int* __restrict__ epk) {
    __shared__ int cur[MAX_B];
    int t = threadIdx.x, blk = blockIdx.x;
    for (int i = t; i < B; i += 256)
        cur[i] = bbase[i] + counts[(size_t)i * CB + blk];
    __syncthreads();
    int s = blk * chunk;
    int e = s + chunk; if (e > E) e = E;
    for (int i = s + 4 * t; i < e; i += 1024) {
        int4 c = *(const int4*)(col + i);
        int4 r = *(const int4*)(row + i);
        int s0 = atomicAdd(&cur[c.x >> BKT_SHIFT], 1); epk[s0] = (r.x << 7) | (c.x & 127);
        int s1 = atomicAdd(&cur[c.y >> BKT_SHIFT], 1); epk[s1] = (r.y << 7) | (c.y & 127);
        int s2 = atomicAdd(&cur[c.z >> BKT_SHIFT], 1); epk[s2] = (r.z << 7) | (c.z & 127);
        int s3 = atomicAdd(&cur[c.w >> BKT_SHIFT], 1); epk[s3] = (r.w << 7) | (c.w & 127);
    }
}

// Pass D: one block per bucket — LDS-stage edges, count, scan, write per-node
// (start,end) pairs + dinv, scatter csr.
__global__ __launch_bounds__(256) void k_bfinal(
    const int* __restrict__ epk, const int* __restrict__ bbase,
    const int* __restrict__ btot, int N,
    int2* __restrict__ offs2, float* __restrict__ dinv, int* __restrict__ csr) {
    __shared__ int sh[FB_CAP];
    __shared__ int cnt[128];
    __shared__ int pre[128];
    __shared__ int cur[128];
    int bkt = blockIdx.x, t = threadIdx.x;
    int s = bbase[bkt];
    int m = btot[bkt];
    int e = s + m;
    int base = bkt << BKT_SHIFT;
    int nn = N - base; if (nn > 128) nn = 128;
    bool fits = (m <= FB_CAP);
    if (t < 128) cnt[t] = 0;
    __syncthreads();
    if (fits) {
        for (int i = t; i < m; i += 256) {
            int u = epk[s + i];
            sh[i] = u;
            atomicAdd(&cnt[u & 127], 1);
        }
    } else {
        for (int i = s + t; i < e; i += 256)
            atomicAdd(&cnt[epk[i] & 127], 1);
    }
    __syncthreads();
    if (t < 128) pre[t] = cnt[t];
    __syncthreads();
    for (int off = 1; off < 128; off <<= 1) {
        int x = (t >= off && t < 128) ? pre[t - off] : 0;
        __syncthreads();
        if (t < 128) pre[t] += x;
        __syncthreads();
    }
    if (t < 128) {
        int ex = pre[t] - cnt[t];
        cur[t] = ex;
        if (t < nn) {
            offs2[base + t] = make_int2(s + ex, s + ex + cnt[t]);
            dinv[base + t] = 1.0f / sqrtf((float)cnt[t] + 1.0f);
        }
    }
    __syncthreads();
    if (fits) {
        for (int i = t; i < m; i += 256) {
            int u = sh[i];
            int slot = atomicAdd(&cur[u & 127], 1);
            csr[s + slot] = u >> 7;
        }
    } else {
        for (int i = s + t; i < e; i += 256) {
            int u = epk[i];
            int slot = atomicAdd(&cur[u & 127], 1);
            csr[s + slot] = u >> 7;
        }
    }
}

// ============ MFMA matmul [N,128]@[128,128] -> bf16 table, scaled by dinv ===
// 64-row blocks. A-tile staged in LDS as bf16 (coalesced global loads, stride
// 136 -> only 2-way LDS conflicts = free). Weights in LDS (32 KB). A-buffer is
// reused as the epilogue transpose buffer. LDS total 49.4 KB -> 3 blocks/CU.
template <int ABF16>
__global__ __launch_bounds__(256) void k_matmul_mfma(
    const float* __restrict__ Af, const ushort_t* __restrict__ Abf,
    const uint4* __restrict__ wfrag, const float* __restrict__ dinv,
    ushort_t* __restrict__ Cb, int N) {
    __shared__ uint4 wfs[2048];                       // 32 KB
    __shared__ __align__(16) ushort_t As[64 * 136];   // 17.4 KB (also epilogue eb)
    int t = threadIdx.x;
    int wv = t >> 6, lane = t & 63;
    int n = lane & 15, quad = lane >> 4;
    int row0 = blockIdx.x * 64;

    for (int i = t; i < 2048; i += 256) wfs[i] = wfrag[i];

    // ---- stage A tile (bf16) into LDS, coalesced ----
    if (ABF16) {
#pragma unroll
        for (int i = 0; i < 4; ++i) {                 // 64 rows x 16 chunks(16B)
            int idx = i * 256 + t;
            int r = idx >> 4, c8 = idx & 15;
            int grow = row0 + r; if (grow >= N) grow = N - 1;
            uint4 u = *(const uint4*)(Abf + (size_t)grow * C_DIM + c8 * 8);
            *(uint4*)&As[r * 136 + c8 * 8] = u;
        }
    } else {
#pragma unroll
        for (int i = 0; i < 8; ++i) {                 // 64 rows x 32 float4
            int idx = i * 256 + t;
            int r = idx >> 5, cq = idx & 31;
            int grow = row0 + r; if (grow >= N) grow = N - 1;
            float4 f = *(const float4*)(Af + (size_t)grow * C_DIM + cq * 4);
            union { ushort_t h[4]; uint2 v; } c;
            c.h[0] = f2bf(f.x); c.h[1] = f2bf(f.y);
            c.h[2] = f2bf(f.z); c.h[3] = f2bf(f.w);
            *(uint2*)&As[r * 136 + cq * 4] = c.v;
        }
    }

    f32x4 acc[8];
#pragma unroll
    for (int i = 0; i < 8; ++i) acc[i] = (f32x4){0.f, 0.f, 0.f, 0.f};

    __syncthreads();

    int rl = wv * 16 + n;                             // this lane's A row (local)
#pragma unroll
    for (int kk = 0; kk < 4; ++kk) {
        union { uint4 v; short8 s; } ca;
        ca.v = *(const uint4*)&As[rl * 136 + kk * 32 + quad * 8];
#pragma unroll
        for (int nt = 0; nt < 8; ++nt) {
            union { uint4 v; short8 s; } cb;
            cb.v = wfs[(nt * 4 + kk) * 64 + lane];
            acc[nt] = __builtin_amdgcn_mfma_f32_16x16x32_bf16(ca.s, cb.s, acc[nt], 0, 0, 0);
        }
    }

    // ---- epilogue: transpose via As (reused), coalesced bf16 stores ----
    __syncthreads();                                  // all A reads done
#pragma unroll
    for (int reg = 0; reg < 4; ++reg) {
        int lr = wv * 16 + quad * 4 + reg;            // local row 0..63
        int grow = row0 + lr;
        float sc = dinv[grow < N ? grow : N - 1];
#pragma unroll
        for (int nt = 0; nt < 8; ++nt)
            As[lr * 136 + nt * 16 + n] = f2bf(acc[nt][reg] * sc);
    }
    __syncthreads();
    int rows = N - row0; if (rows > 64) rows = 64;
    for (int idx = t; idx < 16 * 64; idx += 256) {
        int r = idx >> 4, c8 = idx & 15;
        if (r < rows)
            *(uint4*)(Cb + (size_t)(row0 + r) * C_DIM + c8 * 8) =
                *(const uint4*)&As[r * 136 + c8 * 8];
    }
}

// ---------------- per-node gather-reduce aggregation (bf16 in/out) -----------
// r7 form (fastest measured): one wave per node; 16 lanes cover a 256 B row
// (uint4/lane); quad q takes edge j+4b+q; scalar dword csr loads; 8 fp32 accs;
// shfl_xor butterfly merges the 4 quads.
template <int RELU>
__global__ __launch_bounds__(256) void k_aggregate(
    const ushort_t* __restrict__ hs, const int2* __restrict__ offs2,
    const int* __restrict__ csr, const float* __restrict__ dinv,
    const float* __restrict__ bias, uint4* __restrict__ outV, int N) {
    int node = (blockIdx.x << 2) + (threadIdx.x >> 6);
    if (node >= N) return;
    int t = threadIdx.x & 63;
    int q = t >> 4;         // quad 0..3
    int fs = t & 15;        // feature slice: features 8*fs .. 8*fs+7
    int2 se = offs2[node];
    int s = se.x, e = se.y;

    float acc[8];
    {   // self-loop: quad 0 only
        uint4 u = *(const uint4*)(hs + (size_t)node * C_DIM + fs * 8);
        float v[8];
        v[0] = bf_lo(u.x); v[1] = bf_hi(u.x);
        v[2] = bf_lo(u.y); v[3] = bf_hi(u.y);
        v[4] = bf_lo(u.z); v[5] = bf_hi(u.z);
        v[6] = bf_lo(u.w); v[7] = bf_hi(u.w);
#pragma unroll
        for (int i = 0; i < 8; ++i) acc[i] = (q == 0) ? v[i] : 0.f;
    }

    int j = s;
    for (; j + 16 <= e; j += 16) {          // 16 edges: 4 idx + 4 row loads
        int r[4];
#pragma unroll
        for (int b = 0; b < 4; ++b) r[b] = csr[j + b * 4 + q];
        uint4 u[4];
#pragma unroll
        for (int b = 0; b < 4; ++b)
            u[b] = *(const uint4*)(hs + (size_t)r[b] * C_DIM + fs * 8);
#pragma unroll
        for (int b = 0; b < 4; ++b) accum8(u[b], acc);
    }
    for (; j + 4 <= e; j += 4) {            // 4-edge groups
        int r = csr[j + q];
        uint4 u = *(const uint4*)(hs + (size_t)r * C_DIM + fs * 8);
        accum8(u, acc);
    }
    if (j + q < e) {                        // tail 1-3 edges: one per quad
        int r = csr[j + q];
        uint4 u = *(const uint4*)(hs + (size_t)r * C_DIM + fs * 8);
        accum8(u, acc);
    }

#pragma unroll
    for (int i = 0; i < 8; ++i) {
        acc[i] += __shfl_xor(acc[i], 16);
        acc[i] += __shfl_xor(acc[i], 32);
    }

    if (q == 0) {
        float dn = dinv[node];
        float4 b0 = *(const float4*)(bias + fs * 8);
        float4 b1 = *(const float4*)(bias + fs * 8 + 4);
        float o[8];
        o[0] = dn * acc[0] + b0.x; o[1] = dn * acc[1] + b0.y;
        o[2] = dn * acc[2] + b0.z; o[3] = dn * acc[3] + b0.w;
        o[4] = dn * acc[4] + b1.x; o[5] = dn * acc[5] + b1.y;
        o[6] = dn * acc[6] + b1.z; o[7] = dn * acc[7] + b1.w;
        if (RELU) {
#pragma unroll
            for (int i = 0; i < 8; ++i) o[i] = fmaxf(o[i], 0.f);
        }
        uint4 pk;
        pk.x = (unsigned)f2bf(o[0]) | ((unsigned)f2bf(o[1]) << 16);
        pk.y = (unsigned)f2bf(o[2]) | ((unsigned)f2bf(o[3]) << 16);
        pk.z = (unsigned)f2bf(o[4]) | ((unsigned)f2bf(o[5]) << 16);
        pk.w = (unsigned)f2bf(o[6]) | ((unsigned)f2bf(o[7]) << 16);
        outV[(size_t)node * 16 + fs] = pk;
    }
}

// ---------------- pool stage 1: segmented partial sums (bf16 in) -------------
__global__ __launch_bounds__(128) void k_pool_sum(
    const ushort_t* __restrict__ h, const int* __restrict__ batch, int n,
    float* __restrict__ sums) {
    int r0 = blockIdx.x * POOL_CHUNK;
    int r1 = r0 + POOL_CHUNK; if (r1 > n) r1 = n;
    if (r0 >= n) return;
    int t = threadIdx.x;
    int c = t & 63, rr = t >> 6;
    float2 acc = make_float2(0.f, 0.f);
    int g = batch[r0];
    int i = r0;
    while (i < r1) {
        if (i + 8 <= r1 && batch[i + 7] == g) {
#pragma unroll
            for (int b = 0; b < 4; ++b) {
                unsigned u = *(const unsigned*)(h + (size_t)(i + rr + 2 * b) * C_DIM + c * 2);
                acc.x += bf_lo(u); acc.y += bf_hi(u);
            }
            i += 8;
        } else {
            int bi = batch[i];
            if (bi != g) {
                atomicAdd(&sums[(size_t)g * C_DIM + c * 2], acc.x);
                atomicAdd(&sums[(size_t)g * C_DIM + c * 2 + 1], acc.y);
                acc = make_float2(0.f, 0.f); g = bi;
            }
            if (rr == 0) {
                unsigned u = *(const unsigned*)(h + (size_t)i * C_DIM + c * 2);
                acc.x += bf_lo(u); acc.y += bf_hi(u);
            }
            ++i;
        }
    }
    atomicAdd(&sums[(size_t)g * C_DIM + c * 2], acc.x);
    atomicAdd(&sums[(size_t)g * C_DIM + c * 2 + 1], acc.y);
}

// ---------------- pool stage 2: mean + MLP (128->64->1) ----------------
__global__ __launch_bounds__(128) void k_mlp(
    const float* __restrict__ sums, const int* __restrict__ batch, int n,
    const float* __restrict__ Wm1, const float* __restrict__ bm1,
    const float* __restrict__ Wm2, const float* __restrict__ bm2,
    float* __restrict__ out) {
    int g = blockIdx.x;
    int t = threadIdx.x;
    int lo = 0, hi = n;
    while (lo < hi) { int m = (lo + hi) >> 1; if (batch[m] < g) lo = m + 1; else hi = m; }
    int start = lo;
    lo = start; hi = n;
    while (lo < hi) { int m = (lo + hi) >> 1; if (batch[m] < g + 1) lo = m + 1; else hi = m; }
    float cnt = (float)(lo - start);

    float mean = sums[(size_t)g * C_DIM + t] / fmaxf(cnt, 1.0f);

    __shared__ float m_s[128];
    __shared__ float hid[64];
    m_s[t] = mean;
    __syncthreads();
    if (t < 64) {
        float a = bm1[t];
#pragma unroll 4
        for (int k = 0; k < 128; ++k) a += m_s[k] * Wm1[k * 64 + t];
        hid[t] = fmaxf(a, 0.f) * Wm2[t];
    }
    __syncthreads();
    if (t < 64) {
        float v = hid[t];
        for (int off = 32; off > 0; off >>= 1) v += __shfl_down(v, off);
        if (t == 0) out[g] = v + bm2[0];
    }
}

extern "C" void kernel_launch(void* const* d_in, const int* in_sizes, int n_in,
                              void* d_out, int out_size, void* d_ws, size_t ws_size,
                              hipStream_t stream) {
    const float* x     = (const float*)d_in[0];
    const int*   eidx  = (const int*)d_in[1];
    const int*   batch = (const int*)d_in[2];
    const float* W1    = (const float*)d_in[3];
    const float* b1    = (const float*)d_in[4];
    const float* W2    = (const float*)d_in[5];
    const float* b2    = (const float*)d_in[6];
    const float* Wm1   = (const float*)d_in[7];
    const float* bm1   = (const float*)d_in[8];
    const float* Wm2   = (const float*)d_in[9];
    const float* bm2   = (const float*)d_in[10];

    const int N = in_sizes[2];       // 100000
    const int E = in_sizes[1] / 2;   // 1600000 (E % 4 == 0)
    const int G = out_size;          // 512
    const int B = (N + 127) >> BKT_SHIFT;   // 782 buckets

    char* p = (char*)d_ws;
    auto carve = [&](size_t bytes) {
        char* q = p;
        p += (bytes + 255) & ~(size_t)255;
        return q;
    };
    ushort_t* bufT   = (ushort_t*)carve((size_t)N * C_DIM * sizeof(ushort_t)); // matmul out
    ushort_t* bufA   = (ushort_t*)carve((size_t)N * C_DIM * sizeof(ushort_t)); // agg out
    float*    dinv   = (float*)   carve((size_t)N * sizeof(float));
    int2*     offs2  = (int2*)    carve((size_t)N * sizeof(int2));
    int*      csr    = (int*)     carve((size_t)E * sizeof(int));
    int*      counts = (int*)     carve((size_t)B * CB * sizeof(int));
    int*      btot   = (int*)     carve((size_t)B * sizeof(int));
    int*      bbase  = (int*)     carve((size_t)B * sizeof(int));
    float*    gsums  = (float*)   carve((size_t)G * C_DIM * sizeof(float));
    uint4*    wf1    = (uint4*)   carve(2048 * sizeof(uint4));
    uint4*    wf2    = (uint4*)   carve(2048 * sizeof(uint4));
    int*      cursor = (int*)     carve(sizeof(int));
    // epk (packed (src<<7)|node, 6.4 MB) aliases bufT (dead until matmul1)
    int*      epk    = (int*)bufT;

    const int* erow = eidx;
    const int* ecol = eidx + E;
    const int chunk = (ceil_div(E, CB) + 3) & ~3;   // multiple of 4 for int4 loads

    // --- CSR-by-destination build (fused wfrag + gsums/cursor zeroing) ---
    k_bcount<<<CB + 2, 256, 0, stream>>>(ecol, E, chunk, B, counts,
                                         W1, W2, wf1, wf2, gsums, G * C_DIM, cursor);
    k_bscan<<<B, CB, 0, stream>>>(counts, bbase, btot, cursor);
    k_bscatter<<<CB, 256, 0, stream>>>(erow, ecol, E, chunk, B, counts, bbase, epk);
    k_bfinal<<<B, 256, 0, stream>>>(epk, bbase, btot, N, offs2, dinv, csr);

    // --- conv1 ---
    k_matmul_mfma<0><<<ceil_div(N, 64), 256, 0, stream>>>(x, nullptr, wf1, dinv, bufT, N);
    k_aggregate<1><<<ceil_div(N, 4), 256, 0, stream>>>(bufT, offs2, csr, dinv, b1,
                                                       (uint4*)bufA, N);
    // --- conv2 ---
    k_matmul_mfma<1><<<ceil_div(N, 64), 256, 0, stream>>>(nullptr, bufA, wf2, dinv, bufT, N);
    k_aggregate<0><<<ceil_div(N, 4), 256, 0, stream>>>(bufT, offs2, csr, dinv, b2,
                                                       (uint4*)bufA, N);
    // --- pool (2-stage) + MLP ---
    k_pool_sum<<<ceil_div(N, POOL_CHUNK), 128, 0, stream>>>(bufA, batch, N, gsums);
    k_mlp<<<G, 128, 0, stream>>>(gsums, batch, N, Wm1, bm1, Wm2, bm2, (float*)d_out);
}

// Round 12
// 318.482 us; speedup vs baseline: 1.0590x; 1.0173x over previous
//
#include <hip/hip_runtime.h>
#include <math.h>

#define C_DIM 128
#define POOL_CHUNK 64
#define BKT_SHIFT 7          // 128 nodes per destination bucket
#define MAX_B 1024           // bucket arrays capacity (B = ceil(N/128) = 782)
#define CB 256               // edge chunk blocks
#define CHUNK_MAX 6400       // per-block LDS sort capacity (chunk = 6252)
#define FB_CAP 8192          // bfinal LDS edge-staging capacity (avg bucket ~2048)
typedef unsigned short ushort_t;
typedef __attribute__((ext_vector_type(8))) short short8;
typedef __attribute__((ext_vector_type(4))) float f32x4;

static inline int ceil_div(int a, int b) { return (a + b - 1) / b; }

// bf16 round-to-nearest-even (unbiased — truncation would bias sums)
__device__ inline ushort_t f2bf(float f) {
    union { float f; unsigned u; } v; v.f = f;
    unsigned r = v.u + 0x7FFFu + ((v.u >> 16) & 1u);
    return (ushort_t)(r >> 16);
}
__device__ inline float bf2f(unsigned s) {
    union { unsigned u; float f; } v; v.u = s << 16; return v.f;
}
__device__ inline float bf_lo(unsigned u) {
    union { unsigned v; float f; } c; c.v = u << 16; return c.f;
}
__device__ inline float bf_hi(unsigned u) {
    union { unsigned v; float f; } c; c.v = u & 0xFFFF0000u; return c.f;
}
__device__ inline void accum8(uint4 u, float acc[8]) {
    acc[0] += bf_lo(u.x); acc[1] += bf_hi(u.x);
    acc[2] += bf_lo(u.y); acc[3] += bf_hi(u.y);
    acc[4] += bf_lo(u.z); acc[5] += bf_hi(u.z);
    acc[6] += bf_lo(u.w); acc[7] += bf_hi(u.w);
}

// ============ CSR build: block-local LDS counting sort (dense writes) =======

// Each block sorts its edge chunk by destination bucket entirely in LDS, then
// streams the sorted chunk out DENSE (coalesced). Per-(block,bucket) segment
// descriptors (start within block region, length) are written block-major so
// each block's descriptor writes are contiguous. Blocks CB..CB+1 pack weights.
__global__ __launch_bounds__(256) void k_sortchunk(
    const int* __restrict__ row, const int* __restrict__ col, int E, int chunk,
    int B, int* __restrict__ counts, int* __restrict__ sstart,
    int* __restrict__ epk,
    const float* __restrict__ W1, const float* __restrict__ W2,
    uint4* __restrict__ wf1, uint4* __restrict__ wf2,
    float* __restrict__ gsums, int GC, int* __restrict__ cursor) {
    int t = threadIdx.x, blk = blockIdx.x;
    if (blk >= CB) {   // weight fragment pre-pack
        const float* W = (blk == CB) ? W1 : W2;
        uint4* wf = (blk == CB) ? wf1 : wf2;
        for (int f = t; f < 2048; f += 256) {
            int lane = f & 63, kkn = f >> 6;
            int kk = kkn & 3, nt = kkn >> 2;
            int n = lane & 15, quad = lane >> 4;
            union { ushort_t h[8]; uint4 v; } u;
#pragma unroll
            for (int j = 0; j < 8; ++j)
                u.h[j] = f2bf(W[(size_t)(kk * 32 + quad * 8 + j) * C_DIM + nt * 16 + n]);
            wf[f] = u.v;
        }
        return;
    }
    // zero gsums + cursor (pool_sum runs much later in the stream)
    for (int i = blk * 256 + t; i < GC; i += CB * 256) gsums[i] = 0.f;
    if (blk == 0 && t == 0) *cursor = 0;

    __shared__ int hist[MAX_B];
    __shared__ int hscan[MAX_B];
    __shared__ int sd[256];
    __shared__ int sorted[CHUNK_MAX];

    for (int i = t; i < B; i += 256) hist[i] = 0;
    __syncthreads();
    int s = blk * chunk;                     // chunk % 4 == 0, E % 4 == 0
    int e = s + chunk; if (e > E) e = E;
    for (int i = s + 4 * t; i < e; i += 1024) {
        int4 c = *(const int4*)(col + i);
        atomicAdd(&hist[c.x >> BKT_SHIFT], 1);
        atomicAdd(&hist[c.y >> BKT_SHIFT], 1);
        atomicAdd(&hist[c.z >> BKT_SHIFT], 1);
        atomicAdd(&hist[c.w >> BKT_SHIFT], 1);
    }
    __syncthreads();
    // blocked exclusive scan of hist[0..B) -> hscan
    {
        int base4 = t * 4;
        int vv[4]; int sum = 0;
#pragma unroll
        for (int j = 0; j < 4; ++j) {
            int idx = base4 + j;
            vv[j] = (idx < B) ? hist[idx] : 0;
            sum += vv[j];
        }
        sd[t] = sum;
        __syncthreads();
        for (int off = 1; off < 256; off <<= 1) {
            int x = (t >= off) ? sd[t - off] : 0;
            __syncthreads();
            sd[t] += x;
            __syncthreads();
        }
        int run = sd[t] - sum;
#pragma unroll
        for (int j = 0; j < 4; ++j) {
            int idx = base4 + j;
            if (idx < B) hscan[idx] = run;
            run += vv[j];
        }
    }
    __syncthreads();
    // descriptor matrices (block-major -> dense per-block writes)
    for (int i = t; i < B; i += 256) {
        counts[(size_t)blk * MAX_B + i] = hist[i];
        sstart[(size_t)blk * MAX_B + i] = hscan[i];
    }
    __syncthreads();
    for (int i = t; i < B; i += 256) hist[i] = hscan[i];  // reuse as cursor
    __syncthreads();
    // place edges into sorted LDS (packed (src<<7)|node7)
    for (int i = s + 4 * t; i < e; i += 1024) {
        int4 c = *(const int4*)(col + i);
        int4 r = *(const int4*)(row + i);
        int p0 = atomicAdd(&hist[c.x >> BKT_SHIFT], 1); sorted[p0] = (r.x << 7) | (c.x & 127);
        int p1 = atomicAdd(&hist[c.y >> BKT_SHIFT], 1); sorted[p1] = (r.y << 7) | (c.y & 127);
        int p2 = atomicAdd(&hist[c.z >> BKT_SHIFT], 1); sorted[p2] = (r.z << 7) | (c.z & 127);
        int p3 = atomicAdd(&hist[c.w >> BKT_SHIFT], 1); sorted[p3] = (r.w << 7) | (c.w & 127);
    }
    __syncthreads();
    int cnt = e - s;
    for (int i = t; i < cnt; i += 256) epk[s + i] = sorted[i];  // dense
}

// Bucket totals (reduce over CB segments) + base claim from global cursor.
__global__ __launch_bounds__(CB) void k_btotred(
    const int* __restrict__ counts, int* __restrict__ bbase,
    int* __restrict__ btot, int* __restrict__ cursor) {
    __shared__ int sd[CB];
    int b = blockIdx.x, t = threadIdx.x;
    sd[t] = counts[(size_t)t * MAX_B + b];
    __syncthreads();
    for (int off = CB / 2; off > 0; off >>= 1) {
        if (t < off) sd[t] += sd[t + off];
        __syncthreads();
    }
    if (t == 0) {
        int tot = sd[0];
        btot[b] = tot;
        bbase[b] = atomicAdd(cursor, tot);
    }
}

// Final: per bucket, gather its CB segments (thread t owns block t's segment),
// LDS-stage, per-node count, scan, write (start,end)+dinv, scatter csr.
__global__ __launch_bounds__(256) void k_bfinal(
    const int* __restrict__ epk, const int* __restrict__ counts,
    const int* __restrict__ sstart, const int* __restrict__ bbase,
    const int* __restrict__ btot, int chunk, int N,
    int2* __restrict__ offs2, float* __restrict__ dinv, int* __restrict__ csr) {
    __shared__ int sh[FB_CAP];
    __shared__ int sd[256];
    __shared__ int cnt[128];
    __shared__ int pre[128];
    __shared__ int cur[128];
    int bkt = blockIdx.x, t = threadIdx.x;
    int sbase = bbase[bkt];
    int m = btot[bkt];
    int base = bkt << BKT_SHIFT;
    int nn = N - base; if (nn > 128) nn = 128;

    int segln = counts[(size_t)t * MAX_B + bkt];
    int gs = t * chunk + sstart[(size_t)t * MAX_B + bkt];  // global seg start
    // placement scan over the 256 segment lengths
    sd[t] = segln;
    __syncthreads();
    for (int off = 1; off < 256; off <<= 1) {
        int x = (t >= off) ? sd[t - off] : 0;
        __syncthreads();
        sd[t] += x;
        __syncthreads();
    }
    int place = sd[t] - segln;

    bool fits = (m <= FB_CAP);
    if (t < 128) cnt[t] = 0;
    __syncthreads();
    if (fits) {
        for (int j = 0; j < segln; ++j) {
            int u = epk[gs + j];
            sh[place + j] = u;
            atomicAdd(&cnt[u & 127], 1);
        }
    } else {
        for (int j = 0; j < segln; ++j)
            atomicAdd(&cnt[epk[gs + j] & 127], 1);
    }
    __syncthreads();
    if (t < 128) pre[t] = cnt[t];
    __syncthreads();
    for (int off = 1; off < 128; off <<= 1) {
        int x = (t >= off && t < 128) ? pre[t - off] : 0;
        __syncthreads();
        if (t < 128) pre[t] += x;
        __syncthreads();
    }
    if (t < 128) {
        int ex = pre[t] - cnt[t];
        cur[t] = ex;
        if (t < nn) {
            offs2[base + t] = make_int2(sbase + ex, sbase + ex + cnt[t]);
            dinv[base + t] = 1.0f / sqrtf((float)cnt[t] + 1.0f);
        }
    }
    __syncthreads();
    if (fits) {
        for (int i = t; i < m; i += 256) {
            int u = sh[i];
            int slot = atomicAdd(&cur[u & 127], 1);
            csr[sbase + slot] = u >> 7;
        }
    } else {
        for (int j = 0; j < segln; ++j) {
            int u = epk[gs + j];
            int slot = atomicAdd(&cur[u & 127], 1);
            csr[sbase + slot] = u >> 7;
        }
    }
}

// ============ MFMA matmul [N,128]@[128,128] -> bf16 table, scaled by dinv ===
// 64-row blocks. A-tile staged in LDS as bf16 (coalesced, stride 136 -> 2-way
// conflicts = free). Weights in LDS (32 KB). A-buffer reused for epilogue.
template <int ABF16>
__global__ __launch_bounds__(256) void k_matmul_mfma(
    const float* __restrict__ Af, const ushort_t* __restrict__ Abf,
    const uint4* __restrict__ wfrag, const float* __restrict__ dinv,
    ushort_t* __restrict__ Cb, int N) {
    __shared__ uint4 wfs[2048];                       // 32 KB
    __shared__ __align__(16) ushort_t As[64 * 136];   // 17.4 KB (also epilogue)
    int t = threadIdx.x;
    int wv = t >> 6, lane = t & 63;
    int n = lane & 15, quad = lane >> 4;
    int row0 = blockIdx.x * 64;

    for (int i = t; i < 2048; i += 256) wfs[i] = wfrag[i];

    if (ABF16) {
#pragma unroll
        for (int i = 0; i < 4; ++i) {
            int idx = i * 256 + t;
            int r = idx >> 4, c8 = idx & 15;
            int grow = row0 + r; if (grow >= N) grow = N - 1;
            uint4 u = *(const uint4*)(Abf + (size_t)grow * C_DIM + c8 * 8);
            *(uint4*)&As[r * 136 + c8 * 8] = u;
        }
    } else {
#pragma unroll
        for (int i = 0; i < 8; ++i) {
            int idx = i * 256 + t;
            int r = idx >> 5, cq = idx & 31;
            int grow = row0 + r; if (grow >= N) grow = N - 1;
            float4 f = *(const float4*)(Af + (size_t)grow * C_DIM + cq * 4);
            union { ushort_t h[4]; uint2 v; } c;
            c.h[0] = f2bf(f.x); c.h[1] = f2bf(f.y);
            c.h[2] = f2bf(f.z); c.h[3] = f2bf(f.w);
            *(uint2*)&As[r * 136 + cq * 4] = c.v;
        }
    }

    f32x4 acc[8];
#pragma unroll
    for (int i = 0; i < 8; ++i) acc[i] = (f32x4){0.f, 0.f, 0.f, 0.f};

    __syncthreads();

    int rl = wv * 16 + n;
#pragma unroll
    for (int kk = 0; kk < 4; ++kk) {
        union { uint4 v; short8 s; } ca;
        ca.v = *(const uint4*)&As[rl * 136 + kk * 32 + quad * 8];
#pragma unroll
        for (int nt = 0; nt < 8; ++nt) {
            union { uint4 v; short8 s; } cb;
            cb.v = wfs[(nt * 4 + kk) * 64 + lane];
            acc[nt] = __builtin_amdgcn_mfma_f32_16x16x32_bf16(ca.s, cb.s, acc[nt], 0, 0, 0);
        }
    }

    __syncthreads();
#pragma unroll
    for (int reg = 0; reg < 4; ++reg) {
        int lr = wv * 16 + quad * 4 + reg;
        int grow = row0 + lr;
        float sc = dinv[grow < N ? grow : N - 1];
#pragma unroll
        for (int nt = 0; nt < 8; ++nt)
            As[lr * 136 + nt * 16 + n] = f2bf(acc[nt][reg] * sc);
    }
    __syncthreads();
    int rows = N - row0; if (rows > 64) rows = 64;
    for (int idx = t; idx < 16 * 64; idx += 256) {
        int r = idx >> 4, c8 = idx & 15;
        if (r < rows)
            *(uint4*)(Cb + (size_t)(row0 + r) * C_DIM + c8 * 8) =
                *(const uint4*)&As[r * 136 + c8 * 8];
    }
}

// ---------------- per-node gather-reduce aggregation (bf16 in/out) -----------
// r7 form (fastest measured): one wave per node; 16 lanes cover a 256 B row.
template <int RELU>
__global__ __launch_bounds__(256) void k_aggregate(
    const ushort_t* __restrict__ hs, const int2* __restrict__ offs2,
    const int* __restrict__ csr, const float* __restrict__ dinv,
    const float* __restrict__ bias, uint4* __restrict__ outV, int N) {
    int node = (blockIdx.x << 2) + (threadIdx.x >> 6);
    if (node >= N) return;
    int t = threadIdx.x & 63;
    int q = t >> 4;
    int fs = t & 15;
    int2 se = offs2[node];
    int s = se.x, e = se.y;

    float acc[8];
    {
        uint4 u = *(const uint4*)(hs + (size_t)node * C_DIM + fs * 8);
        float v[8];
        v[0] = bf_lo(u.x); v[1] = bf_hi(u.x);
        v[2] = bf_lo(u.y); v[3] = bf_hi(u.y);
        v[4] = bf_lo(u.z); v[5] = bf_hi(u.z);
        v[6] = bf_lo(u.w); v[7] = bf_hi(u.w);
#pragma unroll
        for (int i = 0; i < 8; ++i) acc[i] = (q == 0) ? v[i] : 0.f;
    }

    int j = s;
    for (; j + 16 <= e; j += 16) {
        int r[4];
#pragma unroll
        for (int b = 0; b < 4; ++b) r[b] = csr[j + b * 4 + q];
        uint4 u[4];
#pragma unroll
        for (int b = 0; b < 4; ++b)
            u[b] = *(const uint4*)(hs + (size_t)r[b] * C_DIM + fs * 8);
#pragma unroll
        for (int b = 0; b < 4; ++b) accum8(u[b], acc);
    }
    for (; j + 4 <= e; j += 4) {
        int r = csr[j + q];
        uint4 u = *(const uint4*)(hs + (size_t)r * C_DIM + fs * 8);
        accum8(u, acc);
    }
    if (j + q < e) {
        int r = csr[j + q];
        uint4 u = *(const uint4*)(hs + (size_t)r * C_DIM + fs * 8);
        accum8(u, acc);
    }

#pragma unroll
    for (int i = 0; i < 8; ++i) {
        acc[i] += __shfl_xor(acc[i], 16);
        acc[i] += __shfl_xor(acc[i], 32);
    }

    if (q == 0) {
        float dn = dinv[node];
        float4 b0 = *(const float4*)(bias + fs * 8);
        float4 b1 = *(const float4*)(bias + fs * 8 + 4);
        float o[8];
        o[0] = dn * acc[0] + b0.x; o[1] = dn * acc[1] + b0.y;
        o[2] = dn * acc[2] + b0.z; o[3] = dn * acc[3] + b0.w;
        o[4] = dn * acc[4] + b1.x; o[5] = dn * acc[5] + b1.y;
        o[6] = dn * acc[6] + b1.z; o[7] = dn * acc[7] + b1.w;
        if (RELU) {
#pragma unroll
            for (int i = 0; i < 8; ++i) o[i] = fmaxf(o[i], 0.f);
        }
        uint4 pk;
        pk.x = (unsigned)f2bf(o[0]) | ((unsigned)f2bf(o[1]) << 16);
        pk.y = (unsigned)f2bf(o[2]) | ((unsigned)f2bf(o[3]) << 16);
        pk.z = (unsigned)f2bf(o[4]) | ((unsigned)f2bf(o[5]) << 16);
        pk.w = (unsigned)f2bf(o[6]) | ((unsigned)f2bf(o[7]) << 16);
        outV[(size_t)node * 16 + fs] = pk;
    }
}

// ---------------- pool stage 1: segmented partial sums (bf16 in) -------------
__global__ __launch_bounds__(128) void k_pool_sum(
    const ushort_t* __restrict__ h, const int* __restrict__ batch, int n,
    float* __restrict__ sums) {
    int r0 = blockIdx.x * POOL_CHUNK;
    int r1 = r0 + POOL_CHUNK; if (r1 > n) r1 = n;
    if (r0 >= n) return;
    int t = threadIdx.x;
    int c = t & 63, rr = t >> 6;
    float2 acc = make_float2(0.f, 0.f);
    int g = batch[r0];
    int i = r0;
    while (i < r1) {
        if (i + 8 <= r1 && batch[i + 7] == g) {
#pragma unroll
            for (int b = 0; b < 4; ++b) {
                unsigned u = *(const unsigned*)(h + (size_t)(i + rr + 2 * b) * C_DIM + c * 2);
                acc.x += bf_lo(u); acc.y += bf_hi(u);
            }
            i += 8;
        } else {
            int bi = batch[i];
            if (bi != g) {
                atomicAdd(&sums[(size_t)g * C_DIM + c * 2], acc.x);
                atomicAdd(&sums[(size_t)g * C_DIM + c * 2 + 1], acc.y);
                acc = make_float2(0.f, 0.f); g = bi;
            }
            if (rr == 0) {
                unsigned u = *(const unsigned*)(h + (size_t)i * C_DIM + c * 2);
                acc.x += bf_lo(u); acc.y += bf_hi(u);
            }
            ++i;
        }
    }
    atomicAdd(&sums[(size_t)g * C_DIM + c * 2], acc.x);
    atomicAdd(&sums[(size_t)g * C_DIM + c * 2 + 1], acc.y);
}

// ---------------- pool stage 2: mean + MLP (128->64->1) ----------------
__global__ __launch_bounds__(128) void k_mlp(
    const float* __restrict__ sums, const int* __restrict__ batch, int n,
    const float* __restrict__ Wm1, const float* __restrict__ bm1,
    const float* __restrict__ Wm2, const float* __restrict__ bm2,
    float* __restrict__ out) {
    int g = blockIdx.x;
    int t = threadIdx.x;
    int lo = 0, hi = n;
    while (lo < hi) { int m = (lo + hi) >> 1; if (batch[m] < g) lo = m + 1; else hi = m; }
    int start = lo;
    lo = start; hi = n;
    while (lo < hi) { int m = (lo + hi) >> 1; if (batch[m] < g + 1) lo = m + 1; else hi = m; }
    float cnt = (float)(lo - start);

    float mean = sums[(size_t)g * C_DIM + t] / fmaxf(cnt, 1.0f);

    __shared__ float m_s[128];
    __shared__ float hid[64];
    m_s[t] = mean;
    __syncthreads();
    if (t < 64) {
        float a = bm1[t];
#pragma unroll 4
        for (int k = 0; k < 128; ++k) a += m_s[k] * Wm1[k * 64 + t];
        hid[t] = fmaxf(a, 0.f) * Wm2[t];
    }
    __syncthreads();
    if (t < 64) {
        float v = hid[t];
        for (int off = 32; off > 0; off >>= 1) v += __shfl_down(v, off);
        if (t == 0) out[g] = v + bm2[0];
    }
}

extern "C" void kernel_launch(void* const* d_in, const int* in_sizes, int n_in,
                              void* d_out, int out_size, void* d_ws, size_t ws_size,
                              hipStream_t stream) {
    const float* x     = (const float*)d_in[0];
    const int*   eidx  = (const int*)d_in[1];
    const int*   batch = (const int*)d_in[2];
    const float* W1    = (const float*)d_in[3];
    const float* b1    = (const float*)d_in[4];
    const float* W2    = (const float*)d_in[5];
    const float* b2    = (const float*)d_in[6];
    const float* Wm1   = (const float*)d_in[7];
    const float* bm1   = (const float*)d_in[8];
    const float* Wm2   = (const float*)d_in[9];
    const float* bm2   = (const float*)d_in[10];

    const int N = in_sizes[2];       // 100000
    const int E = in_sizes[1] / 2;   // 1600000 (E % 4 == 0)
    const int G = out_size;          // 512
    const int B = (N + 127) >> BKT_SHIFT;   // 782 buckets

    char* p = (char*)d_ws;
    auto carve = [&](size_t bytes) {
        char* q = p;
        p += (bytes + 255) & ~(size_t)255;
        return q;
    };
    ushort_t* bufT   = (ushort_t*)carve((size_t)N * C_DIM * sizeof(ushort_t)); // matmul out
    ushort_t* bufA   = (ushort_t*)carve((size_t)N * C_DIM * sizeof(ushort_t)); // agg out
    float*    dinv   = (float*)   carve((size_t)N * sizeof(float));
    int2*     offs2  = (int2*)    carve((size_t)N * sizeof(int2));
    int*      csr    = (int*)     carve((size_t)E * sizeof(int));
    int*      counts = (int*)     carve((size_t)CB * MAX_B * sizeof(int));  // block-major
    int*      sstart = (int*)     carve((size_t)CB * MAX_B * sizeof(int));  // block-major
    int*      btot   = (int*)     carve((size_t)B * sizeof(int));
    int*      bbase  = (int*)     carve((size_t)B * sizeof(int));
    float*    gsums  = (float*)   carve((size_t)G * C_DIM * sizeof(float));
    uint4*    wf1    = (uint4*)   carve(2048 * sizeof(uint4));
    uint4*    wf2    = (uint4*)   carve(2048 * sizeof(uint4));
    int*      cursor = (int*)     carve(sizeof(int));
    // epk (packed (src<<7)|node7, 6.4 MB, block-dense) aliases bufT
    int*      epk    = (int*)bufT;

    const int* erow = eidx;
    const int* ecol = eidx + E;
    const int chunk = (ceil_div(E, CB) + 3) & ~3;   // 6252, fits CHUNK_MAX

    // --- CSR build: block-local LDS sort -> dense writes (no scatter amp) ---
    k_sortchunk<<<CB + 2, 256, 0, stream>>>(erow, ecol, E, chunk, B,
                                            counts, sstart, epk,
                                            W1, W2, wf1, wf2, gsums, G * C_DIM, cursor);
    k_btotred<<<B, CB, 0, stream>>>(counts, bbase, btot, cursor);
    k_bfinal<<<B, 256, 0, stream>>>(epk, counts, sstart, bbase, btot, chunk, N,
                                    offs2, dinv, csr);

    // --- conv1 ---
    k_matmul_mfma<0><<<ceil_div(N, 64), 256, 0, stream>>>(x, nullptr, wf1, dinv, bufT, N);
    k_aggregate<1><<<ceil_div(N, 4), 256, 0, stream>>>(bufT, offs2, csr, dinv, b1,
                                                       (uint4*)bufA, N);
    // --- conv2 ---
    k_matmul_mfma<1><<<ceil_div(N, 64), 256, 0, stream>>>(nullptr, bufA, wf2, dinv, bufT, N);
    k_aggregate<0><<<ceil_div(N, 4), 256, 0, stream>>>(bufT, offs2, csr, dinv, b2,
                                                       (uint4*)bufA, N);
    // --- pool (2-stage) + MLP ---
    k_pool_sum<<<ceil_div(N, POOL_CHUNK), 128, 0, stream>>>(bufA, batch, N, gsums);
    k_mlp<<<G, 128, 0, stream>>>(gsums, batch, N, Wm1, bm1, Wm2, bm2, (float*)d_out);
}

// Round 13
// 318.352 us; speedup vs baseline: 1.0595x; 1.0004x over previous
//
#include <hip/hip_runtime.h>
#include <math.h>

#define C_DIM 128
#define POOL_CHUNK 64
#define BKT_SHIFT 7          // 128 nodes per destination bucket
#define MAX_B 1024           // bucket arrays capacity (B = ceil(N/128) = 782)
#define CB 256               // edge chunk blocks
#define CHUNK_MAX 6400       // per-block LDS sort capacity (chunk = 6252)
#define FB_CAP 8192          // bfinal LDS edge-staging capacity (avg bucket ~2048)
typedef unsigned short ushort_t;
typedef __attribute__((ext_vector_type(8))) short short8;
typedef __attribute__((ext_vector_type(4))) float f32x4;

static inline int ceil_div(int a, int b) { return (a + b - 1) / b; }

// bf16 round-to-nearest-even (unbiased — truncation would bias sums)
__device__ inline ushort_t f2bf(float f) {
    union { float f; unsigned u; } v; v.f = f;
    unsigned r = v.u + 0x7FFFu + ((v.u >> 16) & 1u);
    return (ushort_t)(r >> 16);
}
__device__ inline float bf2f(unsigned s) {
    union { unsigned u; float f; } v; v.u = s << 16; return v.f;
}
__device__ inline float bf_lo(unsigned u) {
    union { unsigned v; float f; } c; c.v = u << 16; return c.f;
}
__device__ inline float bf_hi(unsigned u) {
    union { unsigned v; float f; } c; c.v = u & 0xFFFF0000u; return c.f;
}
__device__ inline void accum8(uint4 u, float acc[8]) {
    acc[0] += bf_lo(u.x); acc[1] += bf_hi(u.x);
    acc[2] += bf_lo(u.y); acc[3] += bf_hi(u.y);
    acc[4] += bf_lo(u.z); acc[5] += bf_hi(u.z);
    acc[6] += bf_lo(u.w); acc[7] += bf_hi(u.w);
}

// ============ CSR build: block-local LDS counting sort (dense writes) =======

// SINGLE global edge read: pass 1 loads row+col once, stages packed edge +
// bucket-id in LDS while histogramming; pass 2 is an LDS->LDS scatter; then a
// dense coalesced stream-out. Blocks CB..CB+1 pack weights instead.
__global__ __launch_bounds__(256) void k_sortchunk(
    const int* __restrict__ row, const int* __restrict__ col, int E, int chunk,
    int B, int* __restrict__ counts, int* __restrict__ sstart,
    int* __restrict__ epk,
    const float* __restrict__ W1, const float* __restrict__ W2,
    uint4* __restrict__ wf1, uint4* __restrict__ wf2,
    float* __restrict__ gsums, int GC, int* __restrict__ cursor) {
    int t = threadIdx.x, blk = blockIdx.x;
    if (blk >= CB) {   // weight fragment pre-pack
        const float* W = (blk == CB) ? W1 : W2;
        uint4* wf = (blk == CB) ? wf1 : wf2;
        for (int f = t; f < 2048; f += 256) {
            int lane = f & 63, kkn = f >> 6;
            int kk = kkn & 3, nt = kkn >> 2;
            int n = lane & 15, quad = lane >> 4;
            union { ushort_t h[8]; uint4 v; } u;
#pragma unroll
            for (int j = 0; j < 8; ++j)
                u.h[j] = f2bf(W[(size_t)(kk * 32 + quad * 8 + j) * C_DIM + nt * 16 + n]);
            wf[f] = u.v;
        }
        return;
    }
    // zero gsums + cursor (consumers run much later in the stream)
    for (int i = blk * 256 + t; i < GC; i += CB * 256) gsums[i] = 0.f;
    if (blk == 0 && t == 0) *cursor = 0;

    __shared__ int hist[MAX_B];                      // 4 KB
    __shared__ int hscan[MAX_B];                     // 4 KB
    __shared__ int sd[256];                          // 1 KB
    __shared__ __align__(16) int ebuf[CHUNK_MAX];    // 25.6 KB packed (r<<7)|(c&127)
    __shared__ __align__(8)  ushort_t bbuf[CHUNK_MAX]; // 12.8 KB bucket ids
    __shared__ int sorted[CHUNK_MAX];                // 25.6 KB

    for (int i = t; i < B; i += 256) hist[i] = 0;
    __syncthreads();
    int s = blk * chunk;                     // chunk % 4 == 0, E % 4 == 0
    int e = s + chunk; if (e > E) e = E;
    int cnt = e - s;                         // multiple of 4
    // pass 1: single global read; stage packed edge + bucket; histogram
    for (int i = s + 4 * t; i < e; i += 1024) {
        int4 c = *(const int4*)(col + i);
        int4 r = *(const int4*)(row + i);
        int li = i - s;
        int4 pk;
        pk.x = (r.x << 7) | (c.x & 127);
        pk.y = (r.y << 7) | (c.y & 127);
        pk.z = (r.z << 7) | (c.z & 127);
        pk.w = (r.w << 7) | (c.w & 127);
        *(int4*)&ebuf[li] = pk;
        ushort4 bk;
        bk.x = (ushort_t)(c.x >> BKT_SHIFT);
        bk.y = (ushort_t)(c.y >> BKT_SHIFT);
        bk.z = (ushort_t)(c.z >> BKT_SHIFT);
        bk.w = (ushort_t)(c.w >> BKT_SHIFT);
        *(ushort4*)&bbuf[li] = bk;
        atomicAdd(&hist[bk.x], 1);
        atomicAdd(&hist[bk.y], 1);
        atomicAdd(&hist[bk.z], 1);
        atomicAdd(&hist[bk.w], 1);
    }
    __syncthreads();
    // blocked exclusive scan of hist[0..B) -> hscan
    {
        int base4 = t * 4;
        int vv[4]; int sum = 0;
#pragma unroll
        for (int j = 0; j < 4; ++j) {
            int idx = base4 + j;
            vv[j] = (idx < B) ? hist[idx] : 0;
            sum += vv[j];
        }
        sd[t] = sum;
        __syncthreads();
        for (int off = 1; off < 256; off <<= 1) {
            int x = (t >= off) ? sd[t - off] : 0;
            __syncthreads();
            sd[t] += x;
            __syncthreads();
        }
        int run = sd[t] - sum;
#pragma unroll
        for (int j = 0; j < 4; ++j) {
            int idx = base4 + j;
            if (idx < B) hscan[idx] = run;
            run += vv[j];
        }
    }
    __syncthreads();
    // descriptor matrices (block-major -> dense per-block writes)
    for (int i = t; i < B; i += 256) {
        counts[(size_t)blk * MAX_B + i] = hist[i];
        sstart[(size_t)blk * MAX_B + i] = hscan[i];
    }
    __syncthreads();
    for (int i = t; i < B; i += 256) hist[i] = hscan[i];  // reuse as cursor
    __syncthreads();
    // pass 2: LDS -> LDS scatter
    for (int i = t; i < cnt; i += 256) {
        int pos = atomicAdd(&hist[bbuf[i]], 1);
        sorted[pos] = ebuf[i];
    }
    __syncthreads();
    // dense stream-out (int4)
    for (int i = t; i * 4 < cnt; i += 256)
        *(int4*)&epk[s + i * 4] = *(const int4*)&sorted[i * 4];
}

// Final: per bucket, self-claim csr base from cursor (order-free), gather its
// CB segments, LDS-stage, per-node count, scan, write (start,end)+dinv, csr.
__global__ __launch_bounds__(256) void k_bfinal(
    const int* __restrict__ epk, const int* __restrict__ counts,
    const int* __restrict__ sstart, int* __restrict__ cursor,
    int chunk, int N,
    int2* __restrict__ offs2, float* __restrict__ dinv, int* __restrict__ csr) {
    __shared__ int sh[FB_CAP];
    __shared__ int sd[256];
    __shared__ int cnt[128];
    __shared__ int pre[128];
    __shared__ int cur[128];
    __shared__ int sbase_s;
    int bkt = blockIdx.x, t = threadIdx.x;
    int base = bkt << BKT_SHIFT;
    int nn = N - base; if (nn > 128) nn = 128;

    int segln = counts[(size_t)t * MAX_B + bkt];
    int gs = t * chunk + sstart[(size_t)t * MAX_B + bkt];  // global seg start
    // placement scan over the 256 segment lengths (also yields bucket total)
    sd[t] = segln;
    __syncthreads();
    for (int off = 1; off < 256; off <<= 1) {
        int x = (t >= off) ? sd[t - off] : 0;
        __syncthreads();
        sd[t] += x;
        __syncthreads();
    }
    int place = sd[t] - segln;
    int m = sd[255];                       // bucket total
    if (t == 255) sbase_s = atomicAdd(cursor, m);
    if (t < 128) cnt[t] = 0;
    __syncthreads();
    int sbase = sbase_s;

    bool fits = (m <= FB_CAP);
    if (fits) {
        for (int j = 0; j < segln; ++j) {
            int u = epk[gs + j];
            sh[place + j] = u;
            atomicAdd(&cnt[u & 127], 1);
        }
    } else {
        for (int j = 0; j < segln; ++j)
            atomicAdd(&cnt[epk[gs + j] & 127], 1);
    }
    __syncthreads();
    if (t < 128) pre[t] = cnt[t];
    __syncthreads();
    for (int off = 1; off < 128; off <<= 1) {
        int x = (t >= off && t < 128) ? pre[t - off] : 0;
        __syncthreads();
        if (t < 128) pre[t] += x;
        __syncthreads();
    }
    if (t < 128) {
        int ex = pre[t] - cnt[t];
        cur[t] = ex;
        if (t < nn) {
            offs2[base + t] = make_int2(sbase + ex, sbase + ex + cnt[t]);
            dinv[base + t] = 1.0f / sqrtf((float)cnt[t] + 1.0f);
        }
    }
    __syncthreads();
    if (fits) {
        for (int i = t; i < m; i += 256) {
            int u = sh[i];
            int slot = atomicAdd(&cur[u & 127], 1);
            csr[sbase + slot] = u >> 7;
        }
    } else {
        for (int j = 0; j < segln; ++j) {
            int u = epk[gs + j];
            int slot = atomicAdd(&cur[u & 127], 1);
            csr[sbase + slot] = u >> 7;
        }
    }
}

// ============ MFMA matmul [N,128]@[128,128] -> bf16 table, scaled by dinv ===
// 128-row blocks: each wave computes TWO 16-row tiles per staged weight (2x
// MFMA per B-frag read, half the per-block weight-stage cost vs 64-row).
// A staged in LDS bf16 (stride 136 -> 2-way conflicts = free); A-buffer reused
// for the epilogue. LDS 66.8 KB -> 2 blocks/CU.
template <int ABF16>
__global__ __launch_bounds__(256) void k_matmul_mfma(
    const float* __restrict__ Af, const ushort_t* __restrict__ Abf,
    const uint4* __restrict__ wfrag, const float* __restrict__ dinv,
    ushort_t* __restrict__ Cb, int N) {
    __shared__ uint4 wfs[2048];                        // 32 KB
    __shared__ __align__(16) ushort_t As[128 * 136];   // 34.8 KB (also epilogue)
    int t = threadIdx.x;
    int wv = t >> 6, lane = t & 63;
    int n = lane & 15, quad = lane >> 4;
    int row0 = blockIdx.x * 128;

    for (int i = t; i < 2048; i += 256) wfs[i] = wfrag[i];

    if (ABF16) {
#pragma unroll
        for (int i = 0; i < 8; ++i) {                  // 128 rows x 16 uint4
            int idx = i * 256 + t;
            int r = idx >> 4, c8 = idx & 15;
            int grow = row0 + r; if (grow >= N) grow = N - 1;
            uint4 u = *(const uint4*)(Abf + (size_t)grow * C_DIM + c8 * 8);
            *(uint4*)&As[r * 136 + c8 * 8] = u;
        }
    } else {
#pragma unroll
        for (int i = 0; i < 16; ++i) {                 // 128 rows x 32 float4
            int idx = i * 256 + t;
            int r = idx >> 5, cq = idx & 31;
            int grow = row0 + r; if (grow >= N) grow = N - 1;
            float4 f = *(const float4*)(Af + (size_t)grow * C_DIM + cq * 4);
            union { ushort_t h[4]; uint2 v; } c;
            c.h[0] = f2bf(f.x); c.h[1] = f2bf(f.y);
            c.h[2] = f2bf(f.z); c.h[3] = f2bf(f.w);
            *(uint2*)&As[r * 136 + cq * 4] = c.v;
        }
    }

    f32x4 acc[2][8];
#pragma unroll
    for (int tl = 0; tl < 2; ++tl)
#pragma unroll
        for (int i = 0; i < 8; ++i) acc[tl][i] = (f32x4){0.f, 0.f, 0.f, 0.f};

    __syncthreads();

    int rl0 = wv * 32 + n;                             // tile0 row
    int rl1 = rl0 + 16;                                // tile1 row
#pragma unroll
    for (int kk = 0; kk < 4; ++kk) {
        union { uint4 v; short8 s; } ca0, ca1;
        ca0.v = *(const uint4*)&As[rl0 * 136 + kk * 32 + quad * 8];
        ca1.v = *(const uint4*)&As[rl1 * 136 + kk * 32 + quad * 8];
#pragma unroll
        for (int nt = 0; nt < 8; ++nt) {
            union { uint4 v; short8 s; } cb;
            cb.v = wfs[(nt * 4 + kk) * 64 + lane];
            acc[0][nt] = __builtin_amdgcn_mfma_f32_16x16x32_bf16(ca0.s, cb.s, acc[0][nt], 0, 0, 0);
            acc[1][nt] = __builtin_amdgcn_mfma_f32_16x16x32_bf16(ca1.s, cb.s, acc[1][nt], 0, 0, 0);
        }
    }

    __syncthreads();                                   // all A reads done
#pragma unroll
    for (int tl = 0; tl < 2; ++tl)
#pragma unroll
    for (int reg = 0; reg < 4; ++reg) {
        int lr = wv * 32 + tl * 16 + quad * 4 + reg;   // local row 0..127
        int grow = row0 + lr;
        float sc = dinv[grow < N ? grow : N - 1];
#pragma unroll
        for (int nt = 0; nt < 8; ++nt)
            As[lr * 136 + nt * 16 + n] = f2bf(acc[tl][nt][reg] * sc);
    }
    __syncthreads();
    int rows = N - row0; if (rows > 128) rows = 128;
#pragma unroll
    for (int i = 0; i < 8; ++i) {
        int idx = i * 256 + t;
        int r = idx >> 4, c8 = idx & 15;
        if (r < rows)
            *(uint4*)(Cb + (size_t)(row0 + r) * C_DIM + c8 * 8) =
                *(const uint4*)&As[r * 136 + c8 * 8];
    }
}

// ---------------- per-node gather-reduce aggregation (bf16 in/out) -----------
// r7 form (fastest measured): one wave per node; 16 lanes cover a 256 B row.
template <int RELU>
__global__ __launch_bounds__(256) void k_aggregate(
    const ushort_t* __restrict__ hs, const int2* __restrict__ offs2,
    const int* __restrict__ csr, const float* __restrict__ dinv,
    const float* __restrict__ bias, uint4* __restrict__ outV, int N) {
    int node = (blockIdx.x << 2) + (threadIdx.x >> 6);
    if (node >= N) return;
    int t = threadIdx.x & 63;
    int q = t >> 4;
    int fs = t & 15;
    int2 se = offs2[node];
    int s = se.x, e = se.y;

    float acc[8];
    {
        uint4 u = *(const uint4*)(hs + (size_t)node * C_DIM + fs * 8);
        float v[8];
        v[0] = bf_lo(u.x); v[1] = bf_hi(u.x);
        v[2] = bf_lo(u.y); v[3] = bf_hi(u.y);
        v[4] = bf_lo(u.z); v[5] = bf_hi(u.z);
        v[6] = bf_lo(u.w); v[7] = bf_hi(u.w);
#pragma unroll
        for (int i = 0; i < 8; ++i) acc[i] = (q == 0) ? v[i] : 0.f;
    }

    int j = s;
    for (; j + 16 <= e; j += 16) {
        int r[4];
#pragma unroll
        for (int b = 0; b < 4; ++b) r[b] = csr[j + b * 4 + q];
        uint4 u[4];
#pragma unroll
        for (int b = 0; b < 4; ++b)
            u[b] = *(const uint4*)(hs + (size_t)r[b] * C_DIM + fs * 8);
#pragma unroll
        for (int b = 0; b < 4; ++b) accum8(u[b], acc);
    }
    for (; j + 4 <= e; j += 4) {
        int r = csr[j + q];
        uint4 u = *(const uint4*)(hs + (size_t)r * C_DIM + fs * 8);
        accum8(u, acc);
    }
    if (j + q < e) {
        int r = csr[j + q];
        uint4 u = *(const uint4*)(hs + (size_t)r * C_DIM + fs * 8);
        accum8(u, acc);
    }

#pragma unroll
    for (int i = 0; i < 8; ++i) {
        acc[i] += __shfl_xor(acc[i], 16);
        acc[i] += __shfl_xor(acc[i], 32);
    }

    if (q == 0) {
        float dn = dinv[node];
        float4 b0 = *(const float4*)(bias + fs * 8);
        float4 b1 = *(const float4*)(bias + fs * 8 + 4);
        float o[8];
        o[0] = dn * acc[0] + b0.x; o[1] = dn * acc[1] + b0.y;
        o[2] = dn * acc[2] + b0.z; o[3] = dn * acc[3] + b0.w;
        o[4] = dn * acc[4] + b1.x; o[5] = dn * acc[5] + b1.y;
        o[6] = dn * acc[6] + b1.z; o[7] = dn * acc[7] + b1.w;
        if (RELU) {
#pragma unroll
            for (int i = 0; i < 8; ++i) o[i] = fmaxf(o[i], 0.f);
        }
        uint4 pk;
        pk.x = (unsigned)f2bf(o[0]) | ((unsigned)f2bf(o[1]) << 16);
        pk.y = (unsigned)f2bf(o[2]) | ((unsigned)f2bf(o[3]) << 16);
        pk.z = (unsigned)f2bf(o[4]) | ((unsigned)f2bf(o[5]) << 16);
        pk.w = (unsigned)f2bf(o[6]) | ((unsigned)f2bf(o[7]) << 16);
        outV[(size_t)node * 16 + fs] = pk;
    }
}

// ---------------- pool stage 1: segmented partial sums (bf16 in) -------------
__global__ __launch_bounds__(128) void k_pool_sum(
    const ushort_t* __restrict__ h, const int* __restrict__ batch, int n,
    float* __restrict__ sums) {
    int r0 = blockIdx.x * POOL_CHUNK;
    int r1 = r0 + POOL_CHUNK; if (r1 > n) r1 = n;
    if (r0 >= n) return;
    int t = threadIdx.x;
    int c = t & 63, rr = t >> 6;
    float2 acc = make_float2(0.f, 0.f);
    int g = batch[r0];
    int i = r0;
    while (i < r1) {
        if (i + 8 <= r1 && batch[i + 7] == g) {
#pragma unroll
            for (int b = 0; b < 4; ++b) {
                unsigned u = *(const unsigned*)(h + (size_t)(i + rr + 2 * b) * C_DIM + c * 2);
                acc.x += bf_lo(u); acc.y += bf_hi(u);
            }
            i += 8;
        } else {
            int bi = batch[i];
            if (bi != g) {
                atomicAdd(&sums[(size_t)g * C_DIM + c * 2], acc.x);
                atomicAdd(&sums[(size_t)g * C_DIM + c * 2 + 1], acc.y);
                acc = make_float2(0.f, 0.f); g = bi;
            }
            if (rr == 0) {
                unsigned u = *(const unsigned*)(h + (size_t)i * C_DIM + c * 2);
                acc.x += bf_lo(u); acc.y += bf_hi(u);
            }
            ++i;
        }
    }
    atomicAdd(&sums[(size_t)g * C_DIM + c * 2], acc.x);
    atomicAdd(&sums[(size_t)g * C_DIM + c * 2 + 1], acc.y);
}

// ---------------- pool stage 2: mean + MLP (128->64->1) ----------------
__global__ __launch_bounds__(128) void k_mlp(
    const float* __restrict__ sums, const int* __restrict__ batch, int n,
    const float* __restrict__ Wm1, const float* __restrict__ bm1,
    const float* __restrict__ Wm2, const float* __restrict__ bm2,
    float* __restrict__ out) {
    int g = blockIdx.x;
    int t = threadIdx.x;
    int lo = 0, hi = n;
    while (lo < hi) { int m = (lo + hi) >> 1; if (batch[m] < g) lo = m + 1; else hi = m; }
    int start = lo;
    lo = start; hi = n;
    while (lo < hi) { int m = (lo + hi) >> 1; if (batch[m] < g + 1) lo = m + 1; else hi = m; }
    float cnt = (float)(lo - start);

    float mean = sums[(size_t)g * C_DIM + t] / fmaxf(cnt, 1.0f);

    __shared__ float m_s[128];
    __shared__ float hid[64];
    m_s[t] = mean;
    __syncthreads();
    if (t < 64) {
        float a = bm1[t];
#pragma unroll 4
        for (int k = 0; k < 128; ++k) a += m_s[k] * Wm1[k * 64 + t];
        hid[t] = fmaxf(a, 0.f) * Wm2[t];
    }
    __syncthreads();
    if (t < 64) {
        float v = hid[t];
        for (int off = 32; off > 0; off >>= 1) v += __shfl_down(v, off);
        if (t == 0) out[g] = v + bm2[0];
    }
}

extern "C" void kernel_launch(void* const* d_in, const int* in_sizes, int n_in,
                              void* d_out, int out_size, void* d_ws, size_t ws_size,
                              hipStream_t stream) {
    const float* x     = (const float*)d_in[0];
    const int*   eidx  = (const int*)d_in[1];
    const int*   batch = (const int*)d_in[2];
    const float* W1    = (const float*)d_in[3];
    const float* b1    = (const float*)d_in[4];
    const float* W2    = (const float*)d_in[5];
    const float* b2    = (const float*)d_in[6];
    const float* Wm1   = (const float*)d_in[7];
    const float* bm1   = (const float*)d_in[8];
    const float* Wm2   = (const float*)d_in[9];
    const float* bm2   = (const float*)d_in[10];

    const int N = in_sizes[2];       // 100000
    const int E = in_sizes[1] / 2;   // 1600000 (E % 4 == 0)
    const int G = out_size;          // 512
    const int B = (N + 127) >> BKT_SHIFT;   // 782 buckets

    char* p = (char*)d_ws;
    auto carve = [&](size_t bytes) {
        char* q = p;
        p += (bytes + 255) & ~(size_t)255;
        return q;
    };
    ushort_t* bufT   = (ushort_t*)carve((size_t)N * C_DIM * sizeof(ushort_t)); // matmul out
    ushort_t* bufA   = (ushort_t*)carve((size_t)N * C_DIM * sizeof(ushort_t)); // agg out
    float*    dinv   = (float*)   carve((size_t)N * sizeof(float));
    int2*     offs2  = (int2*)    carve((size_t)N * sizeof(int2));
    int*      csr    = (int*)     carve((size_t)E * sizeof(int));
    int*      counts = (int*)     carve((size_t)CB * MAX_B * sizeof(int));  // block-major
    int*      sstart = (int*)     carve((size_t)CB * MAX_B * sizeof(int));  // block-major
    float*    gsums  = (float*)   carve((size_t)G * C_DIM * sizeof(float));
    uint4*    wf1    = (uint4*)   carve(2048 * sizeof(uint4));
    uint4*    wf2    = (uint4*)   carve(2048 * sizeof(uint4));
    int*      cursor = (int*)     carve(sizeof(int));
    // epk (packed (src<<7)|node7, 6.4 MB, block-dense) aliases bufT
    int*      epk    = (int*)bufT;

    const int* erow = eidx;
    const int* ecol = eidx + E;
    const int chunk = (ceil_div(E, CB) + 3) & ~3;   // 6252, fits CHUNK_MAX

    // --- CSR build: LDS counting sort, single edge read, dense writes ---
    k_sortchunk<<<CB + 2, 256, 0, stream>>>(erow, ecol, E, chunk, B,
                                            counts, sstart, epk,
                                            W1, W2, wf1, wf2, gsums, G * C_DIM, cursor);
    k_bfinal<<<B, 256, 0, stream>>>(epk, counts, sstart, cursor, chunk, N,
                                    offs2, dinv, csr);

    // --- conv1 ---
    k_matmul_mfma<0><<<ceil_div(N, 128), 256, 0, stream>>>(x, nullptr, wf1, dinv, bufT, N);
    k_aggregate<1><<<ceil_div(N, 4), 256, 0, stream>>>(bufT, offs2, csr, dinv, b1,
                                                       (uint4*)bufA, N);
    // --- conv2 ---
    k_matmul_mfma<1><<<ceil_div(N, 128), 256, 0, stream>>>(nullptr, bufA, wf2, dinv, bufT, N);
    k_aggregate<0><<<ceil_div(N, 4), 256, 0, stream>>>(bufT, offs2, csr, dinv, b2,
                                                       (uint4*)bufA, N);
    // --- pool (2-stage) + MLP ---
    k_pool_sum<<<ceil_div(N, POOL_CHUNK), 128, 0, stream>>>(bufA, batch, N, gsums);
    k_mlp<<<G, 128, 0, stream>>>(gsums, batch, N, Wm1, bm1, Wm2, bm2, (float*)d_out);
}

// Round 14
// 314.217 us; speedup vs baseline: 1.0734x; 1.0132x over previous
//
#include <hip/hip_runtime.h>
#include <math.h>

#define C_DIM 128
#define POOL_CHUNK 64
#define BKT_SHIFT 7          // 128 nodes per destination bucket
#define MAX_B 1024           // bucket arrays capacity (B = ceil(N/128) = 782)
#define CB 256               // edge chunk blocks
#define CHUNK_MAX 6400       // per-block LDS sort capacity (chunk = 6252)
#define FB_CAP 8192          // bfinal LDS edge-staging capacity (avg bucket ~2048)
typedef unsigned short ushort_t;
typedef __attribute__((ext_vector_type(8))) short short8;
typedef __attribute__((ext_vector_type(4))) float f32x4;
typedef __attribute__((ext_vector_type(2))) float f32x2;  // -> v_pk_add_f32

static inline int ceil_div(int a, int b) { return (a + b - 1) / b; }

// bf16 round-to-nearest-even (unbiased — truncation would bias sums)
__device__ inline ushort_t f2bf(float f) {
    union { float f; unsigned u; } v; v.f = f;
    unsigned r = v.u + 0x7FFFu + ((v.u >> 16) & 1u);
    return (ushort_t)(r >> 16);
}
__device__ inline float bf2f(unsigned s) {
    union { unsigned u; float f; } v; v.u = s << 16; return v.f;
}
__device__ inline float bf_lo(unsigned u) {
    union { unsigned v; float f; } c; c.v = u << 16; return c.f;
}
__device__ inline float bf_hi(unsigned u) {
    union { unsigned v; float f; } c; c.v = u & 0xFFFF0000u; return c.f;
}
// packed accumulate: 2 unpack VALU + 1 v_pk_add_f32 per dword (was 2+2)
__device__ inline void accum8pk(uint4 u, f32x2 ac[4]) {
    ac[0] += (f32x2){bf_lo(u.x), bf_hi(u.x)};
    ac[1] += (f32x2){bf_lo(u.y), bf_hi(u.y)};
    ac[2] += (f32x2){bf_lo(u.z), bf_hi(u.z)};
    ac[3] += (f32x2){bf_lo(u.w), bf_hi(u.w)};
}

// ============ CSR build: block-local LDS counting sort (dense writes) =======

// SINGLE global edge read: pass 1 loads row+col once, stages packed edge +
// bucket-id in LDS while histogramming; pass 2 is an LDS->LDS scatter; then a
// dense coalesced stream-out. Blocks CB..CB+1 pack weights instead.
__global__ __launch_bounds__(256) void k_sortchunk(
    const int* __restrict__ row, const int* __restrict__ col, int E, int chunk,
    int B, int* __restrict__ counts, int* __restrict__ sstart,
    int* __restrict__ epk,
    const float* __restrict__ W1, const float* __restrict__ W2,
    uint4* __restrict__ wf1, uint4* __restrict__ wf2,
    float* __restrict__ gsums, int GC, int* __restrict__ cursor) {
    int t = threadIdx.x, blk = blockIdx.x;
    if (blk >= CB) {   // weight fragment pre-pack
        const float* W = (blk == CB) ? W1 : W2;
        uint4* wf = (blk == CB) ? wf1 : wf2;
        for (int f = t; f < 2048; f += 256) {
            int lane = f & 63, kkn = f >> 6;
            int kk = kkn & 3, nt = kkn >> 2;
            int n = lane & 15, quad = lane >> 4;
            union { ushort_t h[8]; uint4 v; } u;
#pragma unroll
            for (int j = 0; j < 8; ++j)
                u.h[j] = f2bf(W[(size_t)(kk * 32 + quad * 8 + j) * C_DIM + nt * 16 + n]);
            wf[f] = u.v;
        }
        return;
    }
    // zero gsums + cursor (consumers run much later in the stream)
    for (int i = blk * 256 + t; i < GC; i += CB * 256) gsums[i] = 0.f;
    if (blk == 0 && t == 0) *cursor = 0;

    __shared__ int hist[MAX_B];                      // 4 KB
    __shared__ int hscan[MAX_B];                     // 4 KB
    __shared__ int sd[256];                          // 1 KB
    __shared__ __align__(16) int ebuf[CHUNK_MAX];    // 25.6 KB packed (r<<7)|(c&127)
    __shared__ __align__(8)  ushort_t bbuf[CHUNK_MAX]; // 12.8 KB bucket ids
    __shared__ int sorted[CHUNK_MAX];                // 25.6 KB

    for (int i = t; i < B; i += 256) hist[i] = 0;
    __syncthreads();
    int s = blk * chunk;                     // chunk % 4 == 0, E % 4 == 0
    int e = s + chunk; if (e > E) e = E;
    int cnt = e - s;                         // multiple of 4
    for (int i = s + 4 * t; i < e; i += 1024) {
        int4 c = *(const int4*)(col + i);
        int4 r = *(const int4*)(row + i);
        int li = i - s;
        int4 pk;
        pk.x = (r.x << 7) | (c.x & 127);
        pk.y = (r.y << 7) | (c.y & 127);
        pk.z = (r.z << 7) | (c.z & 127);
        pk.w = (r.w << 7) | (c.w & 127);
        *(int4*)&ebuf[li] = pk;
        ushort4 bk;
        bk.x = (ushort_t)(c.x >> BKT_SHIFT);
        bk.y = (ushort_t)(c.y >> BKT_SHIFT);
        bk.z = (ushort_t)(c.z >> BKT_SHIFT);
        bk.w = (ushort_t)(c.w >> BKT_SHIFT);
        *(ushort4*)&bbuf[li] = bk;
        atomicAdd(&hist[bk.x], 1);
        atomicAdd(&hist[bk.y], 1);
        atomicAdd(&hist[bk.z], 1);
        atomicAdd(&hist[bk.w], 1);
    }
    __syncthreads();
    // blocked exclusive scan of hist[0..B) -> hscan
    {
        int base4 = t * 4;
        int vv[4]; int sum = 0;
#pragma unroll
        for (int j = 0; j < 4; ++j) {
            int idx = base4 + j;
            vv[j] = (idx < B) ? hist[idx] : 0;
            sum += vv[j];
        }
        sd[t] = sum;
        __syncthreads();
        for (int off = 1; off < 256; off <<= 1) {
            int x = (t >= off) ? sd[t - off] : 0;
            __syncthreads();
            sd[t] += x;
            __syncthreads();
        }
        int run = sd[t] - sum;
#pragma unroll
        for (int j = 0; j < 4; ++j) {
            int idx = base4 + j;
            if (idx < B) hscan[idx] = run;
            run += vv[j];
        }
    }
    __syncthreads();
    for (int i = t; i < B; i += 256) {
        counts[(size_t)blk * MAX_B + i] = hist[i];
        sstart[(size_t)blk * MAX_B + i] = hscan[i];
    }
    __syncthreads();
    for (int i = t; i < B; i += 256) hist[i] = hscan[i];  // reuse as cursor
    __syncthreads();
    for (int i = t; i < cnt; i += 256) {
        int pos = atomicAdd(&hist[bbuf[i]], 1);
        sorted[pos] = ebuf[i];
    }
    __syncthreads();
    for (int i = t; i * 4 < cnt; i += 256)
        *(int4*)&epk[s + i * 4] = *(const int4*)&sorted[i * 4];
}

// Final: per bucket, self-claim csr base from cursor (order-free), gather its
// CB segments, LDS-stage, per-node count, scan, write (start,end)+dinv, csr.
__global__ __launch_bounds__(256) void k_bfinal(
    const int* __restrict__ epk, const int* __restrict__ counts,
    const int* __restrict__ sstart, int* __restrict__ cursor,
    int chunk, int N,
    int2* __restrict__ offs2, float* __restrict__ dinv, int* __restrict__ csr) {
    __shared__ int sh[FB_CAP];
    __shared__ int sd[256];
    __shared__ int cnt[128];
    __shared__ int pre[128];
    __shared__ int cur[128];
    __shared__ int sbase_s;
    int bkt = blockIdx.x, t = threadIdx.x;
    int base = bkt << BKT_SHIFT;
    int nn = N - base; if (nn > 128) nn = 128;

    int segln = counts[(size_t)t * MAX_B + bkt];
    int gs = t * chunk + sstart[(size_t)t * MAX_B + bkt];
    sd[t] = segln;
    __syncthreads();
    for (int off = 1; off < 256; off <<= 1) {
        int x = (t >= off) ? sd[t - off] : 0;
        __syncthreads();
        sd[t] += x;
        __syncthreads();
    }
    int place = sd[t] - segln;
    int m = sd[255];
    if (t == 255) sbase_s = atomicAdd(cursor, m);
    if (t < 128) cnt[t] = 0;
    __syncthreads();
    int sbase = sbase_s;

    bool fits = (m <= FB_CAP);
    if (fits) {
        for (int j = 0; j < segln; ++j) {
            int u = epk[gs + j];
            sh[place + j] = u;
            atomicAdd(&cnt[u & 127], 1);
        }
    } else {
        for (int j = 0; j < segln; ++j)
            atomicAdd(&cnt[epk[gs + j] & 127], 1);
    }
    __syncthreads();
    if (t < 128) pre[t] = cnt[t];
    __syncthreads();
    for (int off = 1; off < 128; off <<= 1) {
        int x = (t >= off && t < 128) ? pre[t - off] : 0;
        __syncthreads();
        if (t < 128) pre[t] += x;
        __syncthreads();
    }
    if (t < 128) {
        int ex = pre[t] - cnt[t];
        cur[t] = ex;
        if (t < nn) {
            offs2[base + t] = make_int2(sbase + ex, sbase + ex + cnt[t]);
            dinv[base + t] = 1.0f / sqrtf((float)cnt[t] + 1.0f);
        }
    }
    __syncthreads();
    if (fits) {
        for (int i = t; i < m; i += 256) {
            int u = sh[i];
            int slot = atomicAdd(&cur[u & 127], 1);
            csr[sbase + slot] = u >> 7;
        }
    } else {
        for (int j = 0; j < segln; ++j) {
            int u = epk[gs + j];
            int slot = atomicAdd(&cur[u & 127], 1);
            csr[sbase + slot] = u >> 7;
        }
    }
}

// ============ MFMA matmul [N,128]@[128,128] -> bf16 table, scaled by dinv ===
// r11-measured shape: 64-row blocks, 49.4 KB LDS -> 3 blocks/CU, 1563 blocks.
template <int ABF16>
__global__ __launch_bounds__(256) void k_matmul_mfma(
    const float* __restrict__ Af, const ushort_t* __restrict__ Abf,
    const uint4* __restrict__ wfrag, const float* __restrict__ dinv,
    ushort_t* __restrict__ Cb, int N) {
    __shared__ uint4 wfs[2048];                       // 32 KB
    __shared__ __align__(16) ushort_t As[64 * 136];   // 17.4 KB (also epilogue)
    int t = threadIdx.x;
    int wv = t >> 6, lane = t & 63;
    int n = lane & 15, quad = lane >> 4;
    int row0 = blockIdx.x * 64;

    for (int i = t; i < 2048; i += 256) wfs[i] = wfrag[i];

    if (ABF16) {
#pragma unroll
        for (int i = 0; i < 4; ++i) {
            int idx = i * 256 + t;
            int r = idx >> 4, c8 = idx & 15;
            int grow = row0 + r; if (grow >= N) grow = N - 1;
            uint4 u = *(const uint4*)(Abf + (size_t)grow * C_DIM + c8 * 8);
            *(uint4*)&As[r * 136 + c8 * 8] = u;
        }
    } else {
#pragma unroll
        for (int i = 0; i < 8; ++i) {
            int idx = i * 256 + t;
            int r = idx >> 5, cq = idx & 31;
            int grow = row0 + r; if (grow >= N) grow = N - 1;
            float4 f = *(const float4*)(Af + (size_t)grow * C_DIM + cq * 4);
            union { ushort_t h[4]; uint2 v; } c;
            c.h[0] = f2bf(f.x); c.h[1] = f2bf(f.y);
            c.h[2] = f2bf(f.z); c.h[3] = f2bf(f.w);
            *(uint2*)&As[r * 136 + cq * 4] = c.v;
        }
    }

    f32x4 acc[8];
#pragma unroll
    for (int i = 0; i < 8; ++i) acc[i] = (f32x4){0.f, 0.f, 0.f, 0.f};

    __syncthreads();

    int rl = wv * 16 + n;
#pragma unroll
    for (int kk = 0; kk < 4; ++kk) {
        union { uint4 v; short8 s; } ca;
        ca.v = *(const uint4*)&As[rl * 136 + kk * 32 + quad * 8];
#pragma unroll
        for (int nt = 0; nt < 8; ++nt) {
            union { uint4 v; short8 s; } cb;
            cb.v = wfs[(nt * 4 + kk) * 64 + lane];
            acc[nt] = __builtin_amdgcn_mfma_f32_16x16x32_bf16(ca.s, cb.s, acc[nt], 0, 0, 0);
        }
    }

    __syncthreads();
#pragma unroll
    for (int reg = 0; reg < 4; ++reg) {
        int lr = wv * 16 + quad * 4 + reg;
        int grow = row0 + lr;
        float sc = dinv[grow < N ? grow : N - 1];
#pragma unroll
        for (int nt = 0; nt < 8; ++nt)
            As[lr * 136 + nt * 16 + n] = f2bf(acc[nt][reg] * sc);
    }
    __syncthreads();
    int rows = N - row0; if (rows > 64) rows = 64;
    for (int idx = t; idx < 16 * 64; idx += 256) {
        int r = idx >> 4, c8 = idx & 15;
        if (r < rows)
            *(uint4*)(Cb + (size_t)(row0 + r) * C_DIM + c8 * 8) =
                *(const uint4*)&As[r * 136 + c8 * 8];
    }
}

// ---------------- per-node gather-reduce aggregation (bf16 in/out) -----------
// r7 load structure (measured optimum) + f32x2 packed accumulators
// (v_pk_add_f32): 12 VALU/edge instead of 16.
template <int RELU>
__global__ __launch_bounds__(256) void k_aggregate(
    const ushort_t* __restrict__ hs, const int2* __restrict__ offs2,
    const int* __restrict__ csr, const float* __restrict__ dinv,
    const float* __restrict__ bias, uint4* __restrict__ outV, int N) {
    int node = (blockIdx.x << 2) + (threadIdx.x >> 6);
    if (node >= N) return;
    int t = threadIdx.x & 63;
    int q = t >> 4;
    int fs = t & 15;
    int2 se = offs2[node];
    int s = se.x, e = se.y;

    f32x2 ac[4];
    {   // self-loop: quad 0 only
        uint4 u = *(const uint4*)(hs + (size_t)node * C_DIM + fs * 8);
        if (q == 0) {
            ac[0] = (f32x2){bf_lo(u.x), bf_hi(u.x)};
            ac[1] = (f32x2){bf_lo(u.y), bf_hi(u.y)};
            ac[2] = (f32x2){bf_lo(u.z), bf_hi(u.z)};
            ac[3] = (f32x2){bf_lo(u.w), bf_hi(u.w)};
        } else {
#pragma unroll
            for (int i = 0; i < 4; ++i) ac[i] = (f32x2){0.f, 0.f};
        }
    }

    int j = s;
    for (; j + 16 <= e; j += 16) {          // 16 edges: 4 idx + 4 row loads
        int r[4];
#pragma unroll
        for (int b = 0; b < 4; ++b) r[b] = csr[j + b * 4 + q];
        uint4 u[4];
#pragma unroll
        for (int b = 0; b < 4; ++b)
            u[b] = *(const uint4*)(hs + (size_t)r[b] * C_DIM + fs * 8);
#pragma unroll
        for (int b = 0; b < 4; ++b) accum8pk(u[b], ac);
    }
    for (; j + 4 <= e; j += 4) {
        int r = csr[j + q];
        uint4 u = *(const uint4*)(hs + (size_t)r * C_DIM + fs * 8);
        accum8pk(u, ac);
    }
    if (j + q < e) {
        int r = csr[j + q];
        uint4 u = *(const uint4*)(hs + (size_t)r * C_DIM + fs * 8);
        accum8pk(u, ac);
    }

#pragma unroll
    for (int i = 0; i < 4; ++i) {
        ac[i].x += __shfl_xor(ac[i].x, 16);
        ac[i].y += __shfl_xor(ac[i].y, 16);
        ac[i].x += __shfl_xor(ac[i].x, 32);
        ac[i].y += __shfl_xor(ac[i].y, 32);
    }

    if (q == 0) {
        float dn = dinv[node];
        float4 b0 = *(const float4*)(bias + fs * 8);
        float4 b1 = *(const float4*)(bias + fs * 8 + 4);
        float o[8];
        o[0] = dn * ac[0].x + b0.x; o[1] = dn * ac[0].y + b0.y;
        o[2] = dn * ac[1].x + b0.z; o[3] = dn * ac[1].y + b0.w;
        o[4] = dn * ac[2].x + b1.x; o[5] = dn * ac[2].y + b1.y;
        o[6] = dn * ac[3].x + b1.z; o[7] = dn * ac[3].y + b1.w;
        if (RELU) {
#pragma unroll
            for (int i = 0; i < 8; ++i) o[i] = fmaxf(o[i], 0.f);
        }
        uint4 pk;
        pk.x = (unsigned)f2bf(o[0]) | ((unsigned)f2bf(o[1]) << 16);
        pk.y = (unsigned)f2bf(o[2]) | ((unsigned)f2bf(o[3]) << 16);
        pk.z = (unsigned)f2bf(o[4]) | ((unsigned)f2bf(o[5]) << 16);
        pk.w = (unsigned)f2bf(o[6]) | ((unsigned)f2bf(o[7]) << 16);
        outV[(size_t)node * 16 + fs] = pk;
    }
}

// ---------------- pool stage 1: segmented partial sums (bf16 in) -------------
__global__ __launch_bounds__(128) void k_pool_sum(
    const ushort_t* __restrict__ h, const int* __restrict__ batch, int n,
    float* __restrict__ sums) {
    int r0 = blockIdx.x * POOL_CHUNK;
    int r1 = r0 + POOL_CHUNK; if (r1 > n) r1 = n;
    if (r0 >= n) return;
    int t = threadIdx.x;
    int c = t & 63, rr = t >> 6;
    float2 acc = make_float2(0.f, 0.f);
    int g = batch[r0];
    int i = r0;
    while (i < r1) {
        if (i + 8 <= r1 && batch[i + 7] == g) {
#pragma unroll
            for (int b = 0; b < 4; ++b) {
                unsigned u = *(const unsigned*)(h + (size_t)(i + rr + 2 * b) * C_DIM + c * 2);
                acc.x += bf_lo(u); acc.y += bf_hi(u);
            }
            i += 8;
        } else {
            int bi = batch[i];
            if (bi != g) {
                atomicAdd(&sums[(size_t)g * C_DIM + c * 2], acc.x);
                atomicAdd(&sums[(size_t)g * C_DIM + c * 2 + 1], acc.y);
                acc = make_float2(0.f, 0.f); g = bi;
            }
            if (rr == 0) {
                unsigned u = *(const unsigned*)(h + (size_t)i * C_DIM + c * 2);
                acc.x += bf_lo(u); acc.y += bf_hi(u);
            }
            ++i;
        }
    }
    atomicAdd(&sums[(size_t)g * C_DIM + c * 2], acc.x);
    atomicAdd(&sums[(size_t)g * C_DIM + c * 2 + 1], acc.y);
}

// ---------------- pool stage 2: mean + MLP (128->64->1) ----------------
__global__ __launch_bounds__(128) void k_mlp(
    const float* __restrict__ sums, const int* __restrict__ batch, int n,
    const float* __restrict__ Wm1, const float* __restrict__ bm1,
    const float* __restrict__ Wm2, const float* __restrict__ bm2,
    float* __restrict__ out) {
    int g = blockIdx.x;
    int t = threadIdx.x;
    int lo = 0, hi = n;
    while (lo < hi) { int m = (lo + hi) >> 1; if (batch[m] < g) lo = m + 1; else hi = m; }
    int start = lo;
    lo = start; hi = n;
    while (lo < hi) { int m = (lo + hi) >> 1; if (batch[m] < g + 1) lo = m + 1; else hi = m; }
    float cnt = (float)(lo - start);

    float mean = sums[(size_t)g * C_DIM + t] / fmaxf(cnt, 1.0f);

    __shared__ float m_s[128];
    __shared__ float hid[64];
    m_s[t] = mean;
    __syncthreads();
    if (t < 64) {
        float a = bm1[t];
#pragma unroll 4
        for (int k = 0; k < 128; ++k) a += m_s[k] * Wm1[k * 64 + t];
        hid[t] = fmaxf(a, 0.f) * Wm2[t];
    }
    __syncthreads();
    if (t < 64) {
        float v = hid[t];
        for (int off = 32; off > 0; off >>= 1) v += __shfl_down(v, off);
        if (t == 0) out[g] = v + bm2[0];
    }
}

extern "C" void kernel_launch(void* const* d_in, const int* in_sizes, int n_in,
                              void* d_out, int out_size, void* d_ws, size_t ws_size,
                              hipStream_t stream) {
    const float* x     = (const float*)d_in[0];
    const int*   eidx  = (const int*)d_in[1];
    const int*   batch = (const int*)d_in[2];
    const float* W1    = (const float*)d_in[3];
    const float* b1    = (const float*)d_in[4];
    const float* W2    = (const float*)d_in[5];
    const float* b2    = (const float*)d_in[6];
    const float* Wm1   = (const float*)d_in[7];
    const float* bm1   = (const float*)d_in[8];
    const float* Wm2   = (const float*)d_in[9];
    const float* bm2   = (const float*)d_in[10];

    const int N = in_sizes[2];       // 100000
    const int E = in_sizes[1] / 2;   // 1600000 (E % 4 == 0)
    const int G = out_size;          // 512
    const int B = (N + 127) >> BKT_SHIFT;   // 782 buckets

    char* p = (char*)d_ws;
    auto carve = [&](size_t bytes) {
        char* q = p;
        p += (bytes + 255) & ~(size_t)255;
        return q;
    };
    ushort_t* bufT   = (ushort_t*)carve((size_t)N * C_DIM * sizeof(ushort_t)); // matmul out
    ushort_t* bufA   = (ushort_t*)carve((size_t)N * C_DIM * sizeof(ushort_t)); // agg out
    float*    dinv   = (float*)   carve((size_t)N * sizeof(float));
    int2*     offs2  = (int2*)    carve((size_t)N * sizeof(int2));
    int*      csr    = (int*)     carve((size_t)E * sizeof(int));
    int*      counts = (int*)     carve((size_t)CB * MAX_B * sizeof(int));  // block-major
    int*      sstart = (int*)     carve((size_t)CB * MAX_B * sizeof(int));  // block-major
    float*    gsums  = (float*)   carve((size_t)G * C_DIM * sizeof(float));
    uint4*    wf1    = (uint4*)   carve(2048 * sizeof(uint4));
    uint4*    wf2    = (uint4*)   carve(2048 * sizeof(uint4));
    int*      cursor = (int*)     carve(sizeof(int));
    // epk (packed (src<<7)|node7, 6.4 MB, block-dense) aliases bufT
    int*      epk    = (int*)bufT;

    const int* erow = eidx;
    const int* ecol = eidx + E;
    const int chunk = (ceil_div(E, CB) + 3) & ~3;   // 6252, fits CHUNK_MAX

    // --- CSR build: LDS counting sort, single edge read, dense writes ---
    k_sortchunk<<<CB + 2, 256, 0, stream>>>(erow, ecol, E, chunk, B,
                                            counts, sstart, epk,
                                            W1, W2, wf1, wf2, gsums, G * C_DIM, cursor);
    k_bfinal<<<B, 256, 0, stream>>>(epk, counts, sstart, cursor, chunk, N,
                                    offs2, dinv, csr);

    // --- conv1 ---
    k_matmul_mfma<0><<<ceil_div(N, 64), 256, 0, stream>>>(x, nullptr, wf1, dinv, bufT, N);
    k_aggregate<1><<<ceil_div(N, 4), 256, 0, stream>>>(bufT, offs2, csr, dinv, b1,
                                                       (uint4*)bufA, N);
    // --- conv2 ---
    k_matmul_mfma<1><<<ceil_div(N, 64), 256, 0, stream>>>(nullptr, bufA, wf2, dinv, bufT, N);
    k_aggregate<0><<<ceil_div(N, 4), 256, 0, stream>>>(bufT, offs2, csr, dinv, b2,
                                                       (uint4*)bufA, N);
    // --- pool (2-stage) + MLP ---
    k_pool_sum<<<ceil_div(N, POOL_CHUNK), 128, 0, stream>>>(bufA, batch, N, gsums);
    k_mlp<<<G, 128, 0, stream>>>(gsums, batch, N, Wm1, bm1, Wm2, bm2, (float*)d_out);
}